// Round 15
// baseline (226.513 us; speedup 1.0000x reference)
//
#include <hip/hip_runtime.h>
#include <stdint.h>
#include <stddef.h>

typedef __bf16 bf16;
typedef __bf16 bf16x4 __attribute__((ext_vector_type(4)));
typedef __bf16 bf16x8 __attribute__((ext_vector_type(8)));
typedef float f32x4 __attribute__((ext_vector_type(4)));
typedef float f32x16 __attribute__((ext_vector_type(16)));
typedef unsigned long long u64;

#define BATCH 4
#define G_LEN 1024
#define S_LEN 4096
#define DM 512
#define NH 8
#define DK 64
#define CIS_WORDS (G_LEN * (S_LEN / 64))   // 65536

__device__ __forceinline__ f32x4 mfma16(bf16x8 a, bf16x8 b, f32x4 c) {
    return __builtin_amdgcn_mfma_f32_16x16x32_bf16(a, b, c, 0, 0, 0);
}
__device__ __forceinline__ f32x16 mfma32(bf16x8 a, bf16x8 b, f32x16 c) {
    return __builtin_amdgcn_mfma_f32_32x32x16_bf16(a, b, c, 0, 0, 0);
}
// v_cvt_pk_bf16_f32: dst.lo = bf16(lo), dst.hi = bf16(hi). No builtin (m240).
__device__ __forceinline__ uint32_t cvtpk(float lo, float hi_) {
    uint32_t r;
    asm("v_cvt_pk_bf16_f32 %0, %1, %2" : "=v"(r) : "v"(lo), "v"(hi_));
    return r;
}
// v_permlane32_swap_b32: a.lanes[32:64] <-> b.lanes[0:32] (gfx950).
__device__ __forceinline__ void pswap(uint32_t& a, uint32_t& b) {
    asm("v_permlane32_swap_b32 %0, %1" : "+v"(a), "+v"(b));
}
__device__ __forceinline__ bf16x8 mk8(uint32_t a, uint32_t b, uint32_t c, uint32_t d) {
    union { uint32_t u[4]; bf16x8 v; } x;
    x.u[0] = a; x.u[1] = b; x.u[2] = c; x.u[3] = d;
    return x.v;
}
// masked exp2 + bf16 pack + permlane redistribute into PV A-fragments.
// Scores arrive pre-scaled by log2(e) (folded into Q projection) -> bare v_exp_f32.
__device__ __forceinline__ void exppack(f32x16& c, uint32_t kw, float& lsum,
                                        bf16x8& pa0, bf16x8& pa1) {
    #pragma unroll
    for (int reg = 0; reg < 16; ++reg) {
        const int bit = (reg & 3) + 8 * (reg >> 2);
        const float e = exp2f(c[reg]);
        c[reg] = ((kw >> bit) & 1u) ? e : 0.f;
    }
    lsum += ((c[0] + c[1]) + (c[2] + c[3])) + ((c[4] + c[5]) + (c[6] + c[7]))
          + ((c[8] + c[9]) + (c[10] + c[11])) + ((c[12] + c[13]) + (c[14] + c[15]));
    uint32_t wa0 = cvtpk(c[0],  c[1]),  wa1 = cvtpk(c[2],  c[3]);
    uint32_t wb0 = cvtpk(c[4],  c[5]),  wb1 = cvtpk(c[6],  c[7]);
    uint32_t wc0 = cvtpk(c[8],  c[9]),  wc1 = cvtpk(c[10], c[11]);
    uint32_t wd0 = cvtpk(c[12], c[13]), wd1 = cvtpk(c[14], c[15]);
    pswap(wa0, wb0); pswap(wa1, wb1); pswap(wc0, wd0); pswap(wc1, wd1);
    pa0 = mk8(wa0, wa1, wb0, wb1);   // s = 8hi + 0..7
    pa1 = mk8(wc0, wc1, wd0, wd1);   // s = 16 + 8hi + 0..7
}
// async global->LDS, 16B/lane. LDS dest is WAVE-UNIFORM base (HW adds lane*16).
__device__ __forceinline__ void stage16(const bf16* g, char* l) {
    __builtin_amdgcn_global_load_lds(
        (const __attribute__((address_space(1))) void*)g,
        (__attribute__((address_space(3))) void*)l, 16, 0, 0);
}

// ---------------------------------------------------------------------------
// cis dtype detection (bool vs int32) — see round 1 notes. flag=1 -> bytes.
// ---------------------------------------------------------------------------
__global__ void detect_cis(const unsigned char* __restrict__ cis, int* __restrict__ flag) {
    int any = 0;
    for (int i = threadIdx.x; i < 16384; i += 64)
        any |= cis[4 * i + 1];
    #pragma unroll
    for (int off = 1; off < 64; off <<= 1) any |= __shfl_xor(any, off);
    if (threadIdx.x == 0) flag[0] = (any != 0) ? 1 : 0;
}

// ---------------------------------------------------------------------------
// Pack cis[g][s] and mask[b][s] into bit-words (one wave per u64 via ballot).
// ---------------------------------------------------------------------------
__global__ __launch_bounds__(256) void pack_masks(
    const void* __restrict__ cisv, const int* __restrict__ mask,
    const int* __restrict__ flag, u64* __restrict__ cbits, u64* __restrict__ mbits)
{
    const int wid  = blockIdx.x * 4 + (threadIdx.x >> 6);
    const int lane = threadIdx.x & 63;
    if (wid < CIS_WORDS) {
        int v;
        if (flag[0]) v = ((const unsigned char*)cisv)[(size_t)wid * 64 + lane];
        else         v = ((const int*)cisv)[(size_t)wid * 64 + lane];
        const u64 bits = __ballot(v != 0);
        if (lane == 0) cbits[wid] = bits;
    } else if (wid < CIS_WORDS + BATCH * (S_LEN / 64)) {
        const int w2 = wid - CIS_WORDS;               // b*64 + sw
        const u64 bits = __ballot(mask[w2 * 64 + lane] != 0);
        if (lane == 0) mbits[w2] = bits;
    }
}

// ---------------------------------------------------------------------------
// 128x128-tile GEMM (round-13, proven): 4 waves 2x2, wave 64x64 out.
// ---------------------------------------------------------------------------
template<int A_IS_BF16, int TRANS_OUT, int OUT_F32, int ROWS_PER_B>
__global__ __launch_bounds__(256) void gemm128(
    const void* __restrict__ Ap, const float* __restrict__ W,
    const float* __restrict__ bias, const float* __restrict__ shift,
    void* __restrict__ Out, float oscale)
{
    __shared__ bf16 As[128][72];
    __shared__ bf16 Bs[128][72];
    const int tid  = threadIdx.x;
    const int lane = tid & 63;
    const int wave = tid >> 6;
    const int l15  = lane & 15;
    const int l4   = lane >> 4;
    const int wr   = wave >> 1;
    const int wc   = wave & 1;
    const int m0   = blockIdx.x * 128;
    const int n0   = blockIdx.y * 128;

    f32x4 acc[4][4] = {};

    for (int kt = 0; kt < DM; kt += 64) {
        #pragma unroll
        for (int i = 0; i < 8; ++i) {
            const int q   = tid + i * 256;
            const int row = q >> 4;
            const int kq  = (q & 15) * 4;
            bf16x4 av;
            if (A_IS_BF16) {
                av = *(const bf16x4*)((const bf16*)Ap + (size_t)(m0 + row) * DM + kt + kq);
            } else {
                const float4 v = *(const float4*)((const float*)Ap + (size_t)(m0 + row) * DM + kt + kq);
                av[0] = (bf16)v.x; av[1] = (bf16)v.y; av[2] = (bf16)v.z; av[3] = (bf16)v.w;
            }
            *(bf16x4*)&As[row][kq] = av;
            const float4 w = *(const float4*)(W + (size_t)(n0 + row) * DM + kt + kq);
            bf16x4 bv;
            bv[0] = (bf16)w.x; bv[1] = (bf16)w.y; bv[2] = (bf16)w.z; bv[3] = (bf16)w.w;
            *(bf16x4*)&Bs[row][kq] = bv;
        }
        __syncthreads();
        #pragma unroll
        for (int ks = 0; ks < 64; ks += 32) {
            bf16x8 af[4];
            #pragma unroll
            for (int mi = 0; mi < 4; ++mi)
                af[mi] = *(const bf16x8*)&As[wr * 64 + mi * 16 + l15][ks + 8 * l4];
            #pragma unroll
            for (int n = 0; n < 4; ++n) {
                const bf16x8 b = *(const bf16x8*)&Bs[wc * 64 + n * 16 + l15][ks + 8 * l4];
                #pragma unroll
                for (int mi = 0; mi < 4; ++mi)
                    acc[mi][n] = mfma16(af[mi], b, acc[mi][n]);
            }
        }
        __syncthreads();
    }

    #pragma unroll
    for (int n = 0; n < 4; ++n) {
        const int col = n0 + wc * 64 + n * 16 + l15;
        const float bv = bias[col];
        #pragma unroll
        for (int mi = 0; mi < 4; ++mi) {
            const int mb = m0 + wr * 64 + mi * 16 + l4 * 4;
            if (TRANS_OUT) {
                const int bb = mb / ROWS_PER_B;
                bf16x4 o;
                #pragma unroll
                for (int r = 0; r < 4; ++r) o[r] = (bf16)((acc[mi][n][r] + bv) * oscale);
                *(bf16x4*)((bf16*)Out + ((size_t)bb * DM + col) * ROWS_PER_B + (mb % ROWS_PER_B)) = o;
            } else {
                #pragma unroll
                for (int r = 0; r < 4; ++r) {
                    const int m = mb + r;
                    float v = acc[mi][n][r] + bv;
                    if (shift) v += shift[(m / ROWS_PER_B) * DM + col];
                    v *= oscale;
                    if (OUT_F32) ((float*)Out)[(size_t)m * DM + col] = v;
                    else         ((bf16*)Out)[(size_t)m * DM + col] = (bf16)v;
                }
            }
        }
    }
}

// ---------------------------------------------------------------------------
// Flash attention v5: single-barrier 3-buffer pipeline + exp2 scores.
// Rounds 12-14: occupancy levers were null (84-86us flat, Occ ~20%); the cost
// is the per-tile rhythm. One s_barrier per tile: with 3 buffers, the barrier
// that publishes tile t also proves everyone finished reading t-1, so staging
// t+2 into buf[(t+2)%3] (last read at t-1) is safe. vmcnt(4) keeps tile t+1's
// loads in flight. exp2f (Q pre-scaled by 0.125*log2e) = bare v_exp_f32.
// ---------------------------------------------------------------------------
__global__ __launch_bounds__(256) void attn_kernel(
    const bf16* __restrict__ Qb, const bf16* __restrict__ Kb,
    const bf16* __restrict__ Vt, const u64* __restrict__ mbits,
    const u64* __restrict__ cbits, bf16* __restrict__ PO, float* __restrict__ PL)
{
    __shared__ __align__(16) char sm[49152];   // 3 x (8KB K | 8KB V)

    const int tid  = threadIdx.x;
    const int lane = tid & 63;
    const int wave = tid >> 6;
    const int l31  = lane & 31;
    const int hi   = lane >> 5;

    // 1024 blocks = 8 XCD x 4 pairs x (8 g-tiles x 4 S-quarters).
    const int flat = blockIdx.x;
    const int xcd  = flat & 7;
    const int slot = flat >> 3;               // 0..127
    const int pr   = xcd * 4 + (slot >> 5);   // (b,h) pair 0..31
    const int sub  = slot & 31;               // gt*4 + squarter
    const int b    = pr >> 3;
    const int h    = pr & 7;
    const int g0   = (sub >> 2) * 128;
    const int tb   = (sub & 3) * 16;          // tile base (S-quarter, 16 tiles)
    const int blkid = pr * 32 + sub;          // scratch slot 0..1023

    // Q B-frags: q = g0 + wave*32 + l31 (Q pre-scaled 0.125*log2e)
    const bf16* qbase = Qb + (size_t)(b * G_LEN + g0 + wave * 32 + l31) * DM + h * DK + 8 * hi;
    const bf16x8 qf0 = *(const bf16x8*)(qbase);
    const bf16x8 qf1 = *(const bf16x8*)(qbase + 16);
    const bf16x8 qf2 = *(const bf16x8*)(qbase + 32);
    const bf16x8 qf3 = *(const bf16x8*)(qbase + 48);

    const bf16* Kh = Kb + (size_t)b * S_LEN * DM + h * DK;
    const bf16* Vh = Vt + (size_t)(b * NH + h) * DK * S_LEN;
    const u64*  mbv = mbits + b * (S_LEN / 64);
    const u64*  cbv = cbits + (size_t)(g0 + wave * 32 + l31) * (S_LEN / 64);

    // Staging: waves 0,1 stage K rows, waves 2,3 stage V rows.
    // lds off = wave*4096 + i*1024 + lane*16 -> row=(wave&1)*32+i*8+(lane>>3),
    // col16=lane&7. Source pre-swizzle col16s = (lane&7)^(row&7) (rule 21).
    const bool isK    = (wave < 2);
    const int rowbase = (wave & 1) * 32 + (lane >> 3);
    const int col16s  = (lane & 7) ^ (rowbase & 7);
    const int swz     = l31 & 7;   // read-side swizzle key

#define STAGE(tt, bufi) do {                                                   \
    char* ldw = sm + (bufi) * 16384 + wave * 4096;                             \
    _Pragma("unroll")                                                          \
    for (int i = 0; i < 4; ++i) {                                              \
        const int row = rowbase + i * 8;                                       \
        const bf16* g = isK                                                    \
            ? (Kh + (size_t)((tt) * 64 + row) * DM + col16s * 8)               \
            : (Vh + (size_t)row * S_LEN + (tt) * 64 + col16s * 8);             \
        stage16(g, ldw + i * 1024);                                            \
    }                                                                          \
} while (0)

    f32x16 accA = {};   // d = l31
    f32x16 accB = {};   // d = 32 + l31
    float lsum = 0.f;

    // prologue: tiles tb, tb+1 in flight (8 loads/thread outstanding)
    STAGE(tb + 0, 0);
    STAGE(tb + 1, 1);

    for (int t = 0; t < 16; ++t) {
        if (t < 15) asm volatile("s_waitcnt vmcnt(4)" ::: "memory");  // my tile-t loads done
        else        asm volatile("s_waitcnt vmcnt(0)" ::: "memory");
        __builtin_amdgcn_s_barrier();   // tile t visible from ALL waves; all done reading t-1
        __builtin_amdgcn_sched_barrier(0);
        if (t + 2 < 16) STAGE(tb + t + 2, (t + 2) % 3);   // buf last read at t-1: safe

        const char* bK = sm + (t % 3) * 16384;
        const char* bV = bK + 8192;

        // ---- QK^T (A = K from LDS, swizzled read): D[s_sub][q]
#define KF(ss, m) (*(const bf16x8*)(bK + ((ss) * 32 + l31) * 128 + (((2 * (m) + hi) ^ swz) * 16)))
        f32x16 c0 = {}, c1 = {};
        c0 = mfma32(KF(0, 0), qf0, c0); c0 = mfma32(KF(0, 1), qf1, c0);
        c0 = mfma32(KF(0, 2), qf2, c0); c0 = mfma32(KF(0, 3), qf3, c0);
        c1 = mfma32(KF(1, 0), qf0, c1); c1 = mfma32(KF(1, 1), qf1, c1);
        c1 = mfma32(KF(1, 2), qf2, c1); c1 = mfma32(KF(1, 3), qf3, c1);

        // ---- masks: one u64 per 64-s tile
        const u64 w64 = cbv[tb + t] & mbv[tb + t];
        const uint32_t kw0 = ((uint32_t)w64) >> (4 * hi);
        const uint32_t kw1 = ((uint32_t)(w64 >> 32)) >> (4 * hi);

        bf16x8 pa0, pa1, pb0, pb1;
        exppack(c0, kw0, lsum, pa0, pa1);
        exppack(c1, kw1, lsum, pb0, pb1);

        // ---- PV (B = V from LDS, swizzled read): acc[q][d]
#define VF(ss, ks, dh) (*(const bf16x8*)(bV + ((dh) * 32 + l31) * 128 + ((((ss) * 4 + (ks) * 2 + hi) ^ swz) * 16)))
        accA = mfma32(pa0, VF(0, 0, 0), accA); accA = mfma32(pa1, VF(0, 1, 0), accA);
        accA = mfma32(pb0, VF(1, 0, 0), accA); accA = mfma32(pb1, VF(1, 1, 0), accA);
        accB = mfma32(pa0, VF(0, 0, 1), accB); accB = mfma32(pa1, VF(0, 1, 1), accB);
        accB = mfma32(pb0, VF(1, 0, 1), accB); accB = mfma32(pb1, VF(1, 1, 1), accB);
    }
#undef KF
#undef VF
#undef STAGE

    // ---- write partials ----
    const float tl = lsum + __shfl_xor(lsum, 32);
    if (hi == 0) PL[blkid * 128 + wave * 32 + l31] = tl;
    bf16* po = PO + (size_t)blkid * 8192 + (wave * 32) * 64;
    #pragma unroll
    for (int reg = 0; reg < 16; ++reg) {
        const int q = (reg & 3) + 8 * (reg >> 2) + 4 * hi;
        po[q * 64 + l31]      = (bf16)accA[reg];
        po[q * 64 + 32 + l31] = (bf16)accB[reg];
    }
}

// ---------------------------------------------------------------------------
// Merge the four S-quarter partials -> AO. 2M elements, 4 per thread.
// ---------------------------------------------------------------------------
__global__ __launch_bounds__(256) void attn_merge(
    const bf16* __restrict__ PO, const float* __restrict__ PL, bf16* __restrict__ AO)
{
    const int idx = (blockIdx.x * 256 + threadIdx.x) * 4;   // 4 consecutive d
    const int row = idx >> 9;          // 0..4095 = b*1024 + g
    const int col = idx & 511;         // h*64 + d
    const int h   = col >> 6;
    const int d   = col & 63;
    const int pr  = (row >> 10) * 8 + h;
    const int gt  = (row & 1023) >> 7;
    const int q   = row & 127;
    const int slot0 = pr * 32 + gt * 4;
    float num[4] = {0.f, 0.f, 0.f, 0.f};
    float pl = 0.f;
    #pragma unroll
    for (int s = 0; s < 4; ++s) {
        const bf16x4 n = *(const bf16x4*)(PO + (size_t)(slot0 + s) * 8192 + q * 64 + d);
        #pragma unroll
        for (int j = 0; j < 4; ++j) num[j] += (float)n[j];
        pl += PL[(slot0 + s) * 128 + q];
    }
    const float inv = pl > 0.f ? 1.f / pl : 0.f;
    bf16x4 o;
    #pragma unroll
    for (int j = 0; j < 4; ++j) o[j] = (bf16)(num[j] * inv);
    *(bf16x4*)(AO + (size_t)row * 512 + col) = o;
}

// ---------------------------------------------------------------------------
// Row LayerNorm: one block per row (512 cols), 256 threads.
// ---------------------------------------------------------------------------
__global__ __launch_bounds__(256) void out_ln(
    const float* __restrict__ Y, const float* __restrict__ gam,
    const float* __restrict__ bet, float* __restrict__ out)
{
    const int row = blockIdx.x;
    const int tid = threadIdx.x;
    const float x0 = Y[(size_t)row * DM + tid];
    const float x1 = Y[(size_t)row * DM + 256 + tid];
    float s  = x0 + x1;
    float sq = x0 * x0 + x1 * x1;
    #pragma unroll
    for (int off = 1; off < 64; off <<= 1) {
        s  += __shfl_xor(s, off);
        sq += __shfl_xor(sq, off);
    }
    __shared__ float ss[4], ssq[4];
    const int wave = tid >> 6;
    if ((tid & 63) == 0) { ss[wave] = s; ssq[wave] = sq; }
    __syncthreads();
    s  = ss[0] + ss[1] + ss[2] + ss[3];
    sq = ssq[0] + ssq[1] + ssq[2] + ssq[3];
    const float mu  = s * (1.f / 512.f);
    const float var = sq * (1.f / 512.f) - mu * mu;
    const float rs  = rsqrtf(var + 1e-5f);
    out[(size_t)row * DM + tid]       = (x0 - mu) * rs * gam[tid] + bet[tid];
    out[(size_t)row * DM + 256 + tid] = (x1 - mu) * rs * gam[tid + 256] + bet[tid + 256];
}

// ---------------------------------------------------------------------------
extern "C" void kernel_launch(void* const* d_in, const int* in_sizes, int n_in,
                              void* d_out, int out_size, void* d_ws, size_t ws_size,
                              hipStream_t stream) {
    const float* queries     = (const float*)d_in[0];   // [4,1024,512]
    const float* keys_values = (const float*)d_in[1];   // [4,4096,512]
    const float* dq          = (const float*)d_in[2];   // [4,1,512]
    const float* dk          = (const float*)d_in[3];   // [4,1,512]
    const int*   mask        = (const int*)d_in[4];     // [4,4096]
    const void*  cis         = d_in[5];                 // [1024,4096] bool (dtype detected)
    const float* wq_w = (const float*)d_in[6];
    const float* wq_b = (const float*)d_in[7];
    const float* wk_w = (const float*)d_in[8];
    const float* wk_b = (const float*)d_in[9];
    const float* wv_w = (const float*)d_in[10];
    const float* wv_b = (const float*)d_in[11];
    const float* wo_w = (const float*)d_in[12];
    const float* wo_b = (const float*)d_in[13];
    const float* ln_g = (const float*)d_in[14];
    const float* ln_b = (const float*)d_in[15];
    float* out = (float*)d_out;

    char* ws = (char*)d_ws;
    bf16*  Qbf = (bf16*)(ws);                                   //  4 MB (pre-scaled x0.125*log2e)
    bf16*  Kbf = (bf16*)(ws + (4u << 20));                      // 16 MB [16384,512]
    bf16*  Vt  = (bf16*)(ws + (20u << 20));                     // 16 MB [4,8,64,4096]
    bf16*  AO  = (bf16*)(ws + (36u << 20));                     //  4 MB [4096,512]
    bf16*  PO  = (bf16*)(ws + (40u << 20));                     // 16 MB partial numerators [1024][8192]
    float* Yw  = (float*)(ws + (40u << 20));                    //  8 MB (overlays PO; PO dead
                                                                //        before O-proj writes Yw)
    int*   cisflag = (int*)(ws + (56u << 20));                  //  4 B
    u64*   mbits   = (u64*)(ws + (56u << 20) + 4096);           //  2 KB [4][64]
    u64*   cbits   = (u64*)(ws + (56u << 20) + 8192);           // 512 KB [1024][64]
    float* PL      = (float*)(ws + (56u << 20) + 544 * 1024);   // 512 KB [1024][128]

    detect_cis<<<1, 64, 0, stream>>>((const unsigned char*)cis, cisflag);
    pack_masks<<<(CIS_WORDS + BATCH * (S_LEN / 64) + 3) / 4, 256, 0, stream>>>(
        cis, mask, cisflag, cbits, mbits);

    // Projections on the 128x128-tile GEMM.
    // Q pre-scaled by (1/sqrt(dk)) * log2(e) so attn uses exp2 directly.
    gemm128<0, 0, 0, 1024><<<dim3(32, 4),  256, 0, stream>>>(queries,     wq_w, wq_b, dq,      Qbf, 0.125f * 1.44269504f);
    gemm128<0, 0, 0, 4096><<<dim3(128, 4), 256, 0, stream>>>(keys_values, wk_w, wk_b, dk,      Kbf, 1.0f);
    gemm128<0, 1, 0, 4096><<<dim3(128, 4), 256, 0, stream>>>(keys_values, wv_w, wv_b, nullptr, Vt,  1.0f);

    // Fused masked flash attention (4-way S-split, 1-barrier 3-buf pipeline)
    attn_kernel<<<1024, 256, 0, stream>>>(Qbf, Kbf, Vt, mbits, cbits, PO, PL);
    attn_merge<<<2048, 256, 0, stream>>>(PO, PL, AO);

    // Output projection (bf16 A) -> f32 scratch (overwrites PO, now dead)
    gemm128<1, 0, 1, 1024><<<dim3(32, 4),  256, 0, stream>>>(AO, wo_w, wo_b, nullptr, Yw, 1.0f);

    // LayerNorm -> d_out
    out_ln<<<4096, 256, 0, stream>>>(Yw, ln_g, ln_b, out);
}

// Round 16
// 219.934 us; speedup vs baseline: 1.0299x; 1.0299x over previous
//
#include <hip/hip_runtime.h>
#include <stdint.h>
#include <stddef.h>

typedef __bf16 bf16;
typedef __bf16 bf16x4 __attribute__((ext_vector_type(4)));
typedef __bf16 bf16x8 __attribute__((ext_vector_type(8)));
typedef float f32x4 __attribute__((ext_vector_type(4)));
typedef float f32x16 __attribute__((ext_vector_type(16)));
typedef unsigned long long u64;

#define BATCH 4
#define G_LEN 1024
#define S_LEN 4096
#define DM 512
#define NH 8
#define DK 64
#define CIS_WORDS (G_LEN * (S_LEN / 64))   // 65536

__device__ __forceinline__ f32x4 mfma16(bf16x8 a, bf16x8 b, f32x4 c) {
    return __builtin_amdgcn_mfma_f32_16x16x32_bf16(a, b, c, 0, 0, 0);
}
__device__ __forceinline__ f32x16 mfma32(bf16x8 a, bf16x8 b, f32x16 c) {
    return __builtin_amdgcn_mfma_f32_32x32x16_bf16(a, b, c, 0, 0, 0);
}
// v_cvt_pk_bf16_f32: dst.lo = bf16(lo), dst.hi = bf16(hi). No builtin (m240).
__device__ __forceinline__ uint32_t cvtpk(float lo, float hi_) {
    uint32_t r;
    asm("v_cvt_pk_bf16_f32 %0, %1, %2" : "=v"(r) : "v"(lo), "v"(hi_));
    return r;
}
// v_permlane32_swap_b32: a.lanes[32:64] <-> b.lanes[0:32] (gfx950).
__device__ __forceinline__ void pswap(uint32_t& a, uint32_t& b) {
    asm("v_permlane32_swap_b32 %0, %1" : "+v"(a), "+v"(b));
}
__device__ __forceinline__ bf16x8 mk8(uint32_t a, uint32_t b, uint32_t c, uint32_t d) {
    union { uint32_t u[4]; bf16x8 v; } x;
    x.u[0] = a; x.u[1] = b; x.u[2] = c; x.u[3] = d;
    return x.v;
}
// masked exp2 + bf16 pack + permlane redistribute into PV A-fragments.
// Scores arrive pre-scaled by log2(e) (folded into Q projection) -> bare v_exp_f32.
__device__ __forceinline__ void exppack(f32x16& c, uint32_t kw, float& lsum,
                                        bf16x8& pa0, bf16x8& pa1) {
    #pragma unroll
    for (int reg = 0; reg < 16; ++reg) {
        const int bit = (reg & 3) + 8 * (reg >> 2);
        const float e = exp2f(c[reg]);
        c[reg] = ((kw >> bit) & 1u) ? e : 0.f;
    }
    lsum += ((c[0] + c[1]) + (c[2] + c[3])) + ((c[4] + c[5]) + (c[6] + c[7]))
          + ((c[8] + c[9]) + (c[10] + c[11])) + ((c[12] + c[13]) + (c[14] + c[15]));
    uint32_t wa0 = cvtpk(c[0],  c[1]),  wa1 = cvtpk(c[2],  c[3]);
    uint32_t wb0 = cvtpk(c[4],  c[5]),  wb1 = cvtpk(c[6],  c[7]);
    uint32_t wc0 = cvtpk(c[8],  c[9]),  wc1 = cvtpk(c[10], c[11]);
    uint32_t wd0 = cvtpk(c[12], c[13]), wd1 = cvtpk(c[14], c[15]);
    pswap(wa0, wb0); pswap(wa1, wb1); pswap(wc0, wd0); pswap(wc1, wd1);
    pa0 = mk8(wa0, wa1, wb0, wb1);   // s = 8hi + 0..7
    pa1 = mk8(wc0, wc1, wd0, wd1);   // s = 16 + 8hi + 0..7
}
// async global->LDS, 16B/lane. LDS dest is WAVE-UNIFORM base (HW adds lane*16).
__device__ __forceinline__ void stage16(const bf16* g, char* l) {
    __builtin_amdgcn_global_load_lds(
        (const __attribute__((address_space(1))) void*)g,
        (__attribute__((address_space(3))) void*)l, 16, 0, 0);
}

// ---------------------------------------------------------------------------
// cis dtype detection (bool vs int32) — see round 1 notes. flag=1 -> bytes.
// ---------------------------------------------------------------------------
__global__ void detect_cis(const unsigned char* __restrict__ cis, int* __restrict__ flag) {
    int any = 0;
    for (int i = threadIdx.x; i < 16384; i += 64)
        any |= cis[4 * i + 1];
    #pragma unroll
    for (int off = 1; off < 64; off <<= 1) any |= __shfl_xor(any, off);
    if (threadIdx.x == 0) flag[0] = (any != 0) ? 1 : 0;
}

// ---------------------------------------------------------------------------
// Pack cis[g][s] and mask[b][s] into bit-words (one wave per u64 via ballot).
// ---------------------------------------------------------------------------
__global__ __launch_bounds__(256) void pack_masks(
    const void* __restrict__ cisv, const int* __restrict__ mask,
    const int* __restrict__ flag, u64* __restrict__ cbits, u64* __restrict__ mbits)
{
    const int wid  = blockIdx.x * 4 + (threadIdx.x >> 6);
    const int lane = threadIdx.x & 63;
    if (wid < CIS_WORDS) {
        int v;
        if (flag[0]) v = ((const unsigned char*)cisv)[(size_t)wid * 64 + lane];
        else         v = ((const int*)cisv)[(size_t)wid * 64 + lane];
        const u64 bits = __ballot(v != 0);
        if (lane == 0) cbits[wid] = bits;
    } else if (wid < CIS_WORDS + BATCH * (S_LEN / 64)) {
        const int w2 = wid - CIS_WORDS;               // b*64 + sw
        const u64 bits = __ballot(mask[w2 * 64 + lane] != 0);
        if (lane == 0) mbits[w2] = bits;
    }
}

// ---------------------------------------------------------------------------
// 128x128-tile GEMM (round-13, proven): 4 waves 2x2, wave 64x64 out.
// Used for Q-proj (f32 in, bf16 out, x0.125*log2e) and O-proj (bf16 in, f32 out).
// ---------------------------------------------------------------------------
template<int A_IS_BF16, int OUT_F32, int ROWS_PER_B>
__global__ __launch_bounds__(256) void gemm128(
    const void* __restrict__ Ap, const float* __restrict__ W,
    const float* __restrict__ bias, const float* __restrict__ shift,
    void* __restrict__ Out, float oscale)
{
    __shared__ bf16 As[128][72];
    __shared__ bf16 Bs[128][72];
    const int tid  = threadIdx.x;
    const int lane = tid & 63;
    const int wave = tid >> 6;
    const int l15  = lane & 15;
    const int l4   = lane >> 4;
    const int wr   = wave >> 1;
    const int wc   = wave & 1;
    const int m0   = blockIdx.x * 128;
    const int n0   = blockIdx.y * 128;

    f32x4 acc[4][4] = {};

    for (int kt = 0; kt < DM; kt += 64) {
        #pragma unroll
        for (int i = 0; i < 8; ++i) {
            const int q   = tid + i * 256;
            const int row = q >> 4;
            const int kq  = (q & 15) * 4;
            bf16x4 av;
            if (A_IS_BF16) {
                av = *(const bf16x4*)((const bf16*)Ap + (size_t)(m0 + row) * DM + kt + kq);
            } else {
                const float4 v = *(const float4*)((const float*)Ap + (size_t)(m0 + row) * DM + kt + kq);
                av[0] = (bf16)v.x; av[1] = (bf16)v.y; av[2] = (bf16)v.z; av[3] = (bf16)v.w;
            }
            *(bf16x4*)&As[row][kq] = av;
            const float4 w = *(const float4*)(W + (size_t)(n0 + row) * DM + kt + kq);
            bf16x4 bv;
            bv[0] = (bf16)w.x; bv[1] = (bf16)w.y; bv[2] = (bf16)w.z; bv[3] = (bf16)w.w;
            *(bf16x4*)&Bs[row][kq] = bv;
        }
        __syncthreads();
        #pragma unroll
        for (int ks = 0; ks < 64; ks += 32) {
            bf16x8 af[4];
            #pragma unroll
            for (int mi = 0; mi < 4; ++mi)
                af[mi] = *(const bf16x8*)&As[wr * 64 + mi * 16 + l15][ks + 8 * l4];
            #pragma unroll
            for (int n = 0; n < 4; ++n) {
                const bf16x8 b = *(const bf16x8*)&Bs[wc * 64 + n * 16 + l15][ks + 8 * l4];
                #pragma unroll
                for (int mi = 0; mi < 4; ++mi)
                    acc[mi][n] = mfma16(af[mi], b, acc[mi][n]);
            }
        }
        __syncthreads();
    }

    #pragma unroll
    for (int n = 0; n < 4; ++n) {
        const int col = n0 + wc * 64 + n * 16 + l15;
        const float bv = bias[col];
        #pragma unroll
        for (int mi = 0; mi < 4; ++mi) {
            const int mb = m0 + wr * 64 + mi * 16 + l4 * 4;
            #pragma unroll
            for (int r = 0; r < 4; ++r) {
                const int m = mb + r;
                float v = acc[mi][n][r] + bv;
                if (shift) v += shift[(m / ROWS_PER_B) * DM + col];
                v *= oscale;
                if (OUT_F32) ((float*)Out)[(size_t)m * DM + col] = v;
                else         ((bf16*)Out)[(size_t)m * DM + col] = (bf16)v;
            }
        }
    }
}

// ---------------------------------------------------------------------------
// Combined K+V projection in ONE dispatch: gridDim.z = 2 (z=0: K with +dk
// shift; z=1: V with transposed epilogue). Same proven gemm128 body; the two
// halves are independent work co-resident on the CUs (4 blocks/CU during the
// KV phase instead of 2+2 sequential) — pure TLP fill, no new math.
// ---------------------------------------------------------------------------
__global__ __launch_bounds__(256) void gemm_kv128(
    const float* __restrict__ X,
    const float* __restrict__ Wk, const float* __restrict__ bk, const float* __restrict__ dkv,
    const float* __restrict__ Wv, const float* __restrict__ bv,
    bf16* __restrict__ OutK, bf16* __restrict__ OutVt)
{
    __shared__ bf16 As[128][72];
    __shared__ bf16 Bs[128][72];
    const int tid  = threadIdx.x;
    const int lane = tid & 63;
    const int wave = tid >> 6;
    const int l15  = lane & 15;
    const int l4   = lane >> 4;
    const int wr   = wave >> 1;
    const int wc   = wave & 1;
    const int m0   = blockIdx.x * 128;
    const int n0   = blockIdx.y * 128;
    const int isV  = blockIdx.z;
    const float* W = isV ? Wv : Wk;

    f32x4 acc[4][4] = {};

    for (int kt = 0; kt < DM; kt += 64) {
        #pragma unroll
        for (int i = 0; i < 8; ++i) {
            const int q   = tid + i * 256;
            const int row = q >> 4;
            const int kq  = (q & 15) * 4;
            const float4 x = *(const float4*)(X + (size_t)(m0 + row) * DM + kt + kq);
            bf16x4 av;
            av[0] = (bf16)x.x; av[1] = (bf16)x.y; av[2] = (bf16)x.z; av[3] = (bf16)x.w;
            *(bf16x4*)&As[row][kq] = av;
            const float4 w = *(const float4*)(W + (size_t)(n0 + row) * DM + kt + kq);
            bf16x4 bvv;
            bvv[0] = (bf16)w.x; bvv[1] = (bf16)w.y; bvv[2] = (bf16)w.z; bvv[3] = (bf16)w.w;
            *(bf16x4*)&Bs[row][kq] = bvv;
        }
        __syncthreads();
        #pragma unroll
        for (int ks = 0; ks < 64; ks += 32) {
            bf16x8 af[4];
            #pragma unroll
            for (int mi = 0; mi < 4; ++mi)
                af[mi] = *(const bf16x8*)&As[wr * 64 + mi * 16 + l15][ks + 8 * l4];
            #pragma unroll
            for (int n = 0; n < 4; ++n) {
                const bf16x8 b = *(const bf16x8*)&Bs[wc * 64 + n * 16 + l15][ks + 8 * l4];
                #pragma unroll
                for (int mi = 0; mi < 4; ++mi)
                    acc[mi][n] = mfma16(af[mi], b, acc[mi][n]);
            }
        }
        __syncthreads();
    }

    #pragma unroll
    for (int n = 0; n < 4; ++n) {
        const int col = n0 + wc * 64 + n * 16 + l15;
        const float bkc = bk[col];
        const float bvc = bv[col];
        #pragma unroll
        for (int mi = 0; mi < 4; ++mi) {
            const int mb = m0 + wr * 64 + mi * 16 + l4 * 4;   // 4-aligned
            const int bb = mb >> 12;                          // batch = m / 4096
            if (isV) {
                bf16x4 o;
                #pragma unroll
                for (int r = 0; r < 4; ++r) o[r] = (bf16)(acc[mi][n][r] + bvc);
                *(bf16x4*)(OutVt + ((size_t)bb * DM + col) * 4096 + (mb & 4095)) = o;
            } else {
                const float sh = dkv[bb * DM + col];
                #pragma unroll
                for (int r = 0; r < 4; ++r)
                    OutK[(size_t)(mb + r) * DM + col] = (bf16)(acc[mi][n][r] + bkc + sh);
            }
        }
    }
}

// ---------------------------------------------------------------------------
// Flash attention v4b: round-14 structure (proven 84us) + exp2 scores.
// 4-way S-split, grid 1024 (= 8 XCD x 4 pairs x 8 g-tiles x 4 S-quarters).
// LDS 2 x 16KB double-buffer; two barriers per tile with vmcnt(4) AFTER the
// next-tile STAGE issue (round-15 lesson: hoisting the wait above a single
// barrier serializes the block on the slowest stager; revert).
// ---------------------------------------------------------------------------
__global__ __launch_bounds__(256) void attn_kernel(
    const bf16* __restrict__ Qb, const bf16* __restrict__ Kb,
    const bf16* __restrict__ Vt, const u64* __restrict__ mbits,
    const u64* __restrict__ cbits, bf16* __restrict__ PO, float* __restrict__ PL)
{
    __shared__ __align__(16) char sm[32768];   // 2 x (8KB K | 8KB V)

    const int tid  = threadIdx.x;
    const int lane = tid & 63;
    const int wave = tid >> 6;
    const int l31  = lane & 31;
    const int hi   = lane >> 5;

    // 1024 blocks = 8 XCD x 4 pairs x (8 g-tiles x 4 S-quarters).
    const int flat = blockIdx.x;
    const int xcd  = flat & 7;
    const int slot = flat >> 3;               // 0..127
    const int pr   = xcd * 4 + (slot >> 5);   // (b,h) pair 0..31
    const int sub  = slot & 31;               // gt*4 + squarter
    const int b    = pr >> 3;
    const int h    = pr & 7;
    const int g0   = (sub >> 2) * 128;
    const int tb   = (sub & 3) * 16;          // tile base (S-quarter, 16 tiles)
    const int blkid = pr * 32 + sub;          // scratch slot 0..1023

    // Q B-frags: q = g0 + wave*32 + l31 (Q pre-scaled 0.125*log2e)
    const bf16* qbase = Qb + (size_t)(b * G_LEN + g0 + wave * 32 + l31) * DM + h * DK + 8 * hi;
    const bf16x8 qf0 = *(const bf16x8*)(qbase);
    const bf16x8 qf1 = *(const bf16x8*)(qbase + 16);
    const bf16x8 qf2 = *(const bf16x8*)(qbase + 32);
    const bf16x8 qf3 = *(const bf16x8*)(qbase + 48);

    const bf16* Kh = Kb + (size_t)b * S_LEN * DM + h * DK;
    const bf16* Vh = Vt + (size_t)(b * NH + h) * DK * S_LEN;
    const u64*  mbv = mbits + b * (S_LEN / 64);
    const u64*  cbv = cbits + (size_t)(g0 + wave * 32 + l31) * (S_LEN / 64);

    // Staging: waves 0,1 stage K rows, waves 2,3 stage V rows.
    // lds off = wave*4096 + i*1024 + lane*16 -> row=(wave&1)*32+i*8+(lane>>3),
    // col16=lane&7. Source pre-swizzle col16s = (lane&7)^(row&7) (rule 21).
    const bool isK    = (wave < 2);
    const int rowbase = (wave & 1) * 32 + (lane >> 3);
    const int col16s  = (lane & 7) ^ (rowbase & 7);
    const int swz     = l31 & 7;   // read-side swizzle key

#define STAGE(tt, bufi) do {                                                   \
    char* ldw = sm + (bufi) * 16384 + wave * 4096;                             \
    _Pragma("unroll")                                                          \
    for (int i = 0; i < 4; ++i) {                                              \
        const int row = rowbase + i * 8;                                       \
        const bf16* g = isK                                                    \
            ? (Kh + (size_t)((tt) * 64 + row) * DM + col16s * 8)               \
            : (Vh + (size_t)row * S_LEN + (tt) * 64 + col16s * 8);             \
        stage16(g, ldw + i * 1024);                                            \
    }                                                                          \
} while (0)

    f32x16 accA = {};   // d = l31
    f32x16 accB = {};   // d = 32 + l31
    float lsum = 0.f;

    // prologue: tile tb in flight
    STAGE(tb + 0, 0);

    for (int t = 0; t < 16; ++t) {
        __builtin_amdgcn_s_barrier();              // all waves done reading buf[(t+1)&1]
        __builtin_amdgcn_sched_barrier(0);
        if (t + 1 < 16) {
            STAGE(tb + t + 1, (t + 1) & 1);
            asm volatile("s_waitcnt vmcnt(4)" ::: "memory");   // tile t staged; t+1 in flight
        } else {
            asm volatile("s_waitcnt vmcnt(0)" ::: "memory");
        }
        __builtin_amdgcn_s_barrier();              // buf[t&1] staged for all waves
        __builtin_amdgcn_sched_barrier(0);

        const char* bK = sm + (t & 1) * 16384;
        const char* bV = bK + 8192;

        // ---- QK^T (A = K from LDS, swizzled read): D[s_sub][q]
#define KF(ss, m) (*(const bf16x8*)(bK + ((ss) * 32 + l31) * 128 + (((2 * (m) + hi) ^ swz) * 16)))
        f32x16 c0 = {}, c1 = {};
        c0 = mfma32(KF(0, 0), qf0, c0); c0 = mfma32(KF(0, 1), qf1, c0);
        c0 = mfma32(KF(0, 2), qf2, c0); c0 = mfma32(KF(0, 3), qf3, c0);
        c1 = mfma32(KF(1, 0), qf0, c1); c1 = mfma32(KF(1, 1), qf1, c1);
        c1 = mfma32(KF(1, 2), qf2, c1); c1 = mfma32(KF(1, 3), qf3, c1);

        // ---- masks: one u64 per 64-s tile
        const u64 w64 = cbv[tb + t] & mbv[tb + t];
        const uint32_t kw0 = ((uint32_t)w64) >> (4 * hi);
        const uint32_t kw1 = ((uint32_t)(w64 >> 32)) >> (4 * hi);

        bf16x8 pa0, pa1, pb0, pb1;
        exppack(c0, kw0, lsum, pa0, pa1);
        exppack(c1, kw1, lsum, pb0, pb1);

        // ---- PV (B = V from LDS, swizzled read): acc[q][d]
#define VF(ss, ks, dh) (*(const bf16x8*)(bV + ((dh) * 32 + l31) * 128 + ((((ss) * 4 + (ks) * 2 + hi) ^ swz) * 16)))
        accA = mfma32(pa0, VF(0, 0, 0), accA); accA = mfma32(pa1, VF(0, 1, 0), accA);
        accA = mfma32(pb0, VF(1, 0, 0), accA); accA = mfma32(pb1, VF(1, 1, 0), accA);
        accB = mfma32(pa0, VF(0, 0, 1), accB); accB = mfma32(pa1, VF(0, 1, 1), accB);
        accB = mfma32(pb0, VF(1, 0, 1), accB); accB = mfma32(pb1, VF(1, 1, 1), accB);
    }
#undef KF
#undef VF
#undef STAGE

    // ---- write partials ----
    const float tl = lsum + __shfl_xor(lsum, 32);
    if (hi == 0) PL[blkid * 128 + wave * 32 + l31] = tl;
    bf16* po = PO + (size_t)blkid * 8192 + (wave * 32) * 64;
    #pragma unroll
    for (int reg = 0; reg < 16; ++reg) {
        const int q = (reg & 3) + 8 * (reg >> 2) + 4 * hi;
        po[q * 64 + l31]      = (bf16)accA[reg];
        po[q * 64 + 32 + l31] = (bf16)accB[reg];
    }
}

// ---------------------------------------------------------------------------
// Merge the four S-quarter partials -> AO. 2M elements, 4 per thread.
// ---------------------------------------------------------------------------
__global__ __launch_bounds__(256) void attn_merge(
    const bf16* __restrict__ PO, const float* __restrict__ PL, bf16* __restrict__ AO)
{
    const int idx = (blockIdx.x * 256 + threadIdx.x) * 4;   // 4 consecutive d
    const int row = idx >> 9;          // 0..4095 = b*1024 + g
    const int col = idx & 511;         // h*64 + d
    const int h   = col >> 6;
    const int d   = col & 63;
    const int pr  = (row >> 10) * 8 + h;
    const int gt  = (row & 1023) >> 7;
    const int q   = row & 127;
    const int slot0 = pr * 32 + gt * 4;
    float num[4] = {0.f, 0.f, 0.f, 0.f};
    float pl = 0.f;
    #pragma unroll
    for (int s = 0; s < 4; ++s) {
        const bf16x4 n = *(const bf16x4*)(PO + (size_t)(slot0 + s) * 8192 + q * 64 + d);
        #pragma unroll
        for (int j = 0; j < 4; ++j) num[j] += (float)n[j];
        pl += PL[(slot0 + s) * 128 + q];
    }
    const float inv = pl > 0.f ? 1.f / pl : 0.f;
    bf16x4 o;
    #pragma unroll
    for (int j = 0; j < 4; ++j) o[j] = (bf16)(num[j] * inv);
    *(bf16x4*)(AO + (size_t)row * 512 + col) = o;
}

// ---------------------------------------------------------------------------
// Row LayerNorm: one block per row (512 cols), 256 threads.
// ---------------------------------------------------------------------------
__global__ __launch_bounds__(256) void out_ln(
    const float* __restrict__ Y, const float* __restrict__ gam,
    const float* __restrict__ bet, float* __restrict__ out)
{
    const int row = blockIdx.x;
    const int tid = threadIdx.x;
    const float x0 = Y[(size_t)row * DM + tid];
    const float x1 = Y[(size_t)row * DM + 256 + tid];
    float s  = x0 + x1;
    float sq = x0 * x0 + x1 * x1;
    #pragma unroll
    for (int off = 1; off < 64; off <<= 1) {
        s  += __shfl_xor(s, off);
        sq += __shfl_xor(sq, off);
    }
    __shared__ float ss[4], ssq[4];
    const int wave = tid >> 6;
    if ((tid & 63) == 0) { ss[wave] = s; ssq[wave] = sq; }
    __syncthreads();
    s  = ss[0] + ss[1] + ss[2] + ss[3];
    sq = ssq[0] + ssq[1] + ssq[2] + ssq[3];
    const float mu  = s * (1.f / 512.f);
    const float var = sq * (1.f / 512.f) - mu * mu;
    const float rs  = rsqrtf(var + 1e-5f);
    out[(size_t)row * DM + tid]       = (x0 - mu) * rs * gam[tid] + bet[tid];
    out[(size_t)row * DM + 256 + tid] = (x1 - mu) * rs * gam[tid + 256] + bet[tid + 256];
}

// ---------------------------------------------------------------------------
extern "C" void kernel_launch(void* const* d_in, const int* in_sizes, int n_in,
                              void* d_out, int out_size, void* d_ws, size_t ws_size,
                              hipStream_t stream) {
    const float* queries     = (const float*)d_in[0];   // [4,1024,512]
    const float* keys_values = (const float*)d_in[1];   // [4,4096,512]
    const float* dq          = (const float*)d_in[2];   // [4,1,512]
    const float* dk          = (const float*)d_in[3];   // [4,1,512]
    const int*   mask        = (const int*)d_in[4];     // [4,4096]
    const void*  cis         = d_in[5];                 // [1024,4096] bool (dtype detected)
    const float* wq_w = (const float*)d_in[6];
    const float* wq_b = (const float*)d_in[7];
    const float* wk_w = (const float*)d_in[8];
    const float* wk_b = (const float*)d_in[9];
    const float* wv_w = (const float*)d_in[10];
    const float* wv_b = (const float*)d_in[11];
    const float* wo_w = (const float*)d_in[12];
    const float* wo_b = (const float*)d_in[13];
    const float* ln_g = (const float*)d_in[14];
    const float* ln_b = (const float*)d_in[15];
    float* out = (float*)d_out;

    char* ws = (char*)d_ws;
    bf16*  Qbf = (bf16*)(ws);                                   //  4 MB (pre-scaled x0.125*log2e)
    bf16*  Kbf = (bf16*)(ws + (4u << 20));                      // 16 MB [16384,512]
    bf16*  Vt  = (bf16*)(ws + (20u << 20));                     // 16 MB [4,8,64,4096]
    bf16*  AO  = (bf16*)(ws + (36u << 20));                     //  4 MB [4096,512]
    bf16*  PO  = (bf16*)(ws + (40u << 20));                     // 16 MB partial numerators [1024][8192]
    float* Yw  = (float*)(ws + (40u << 20));                    //  8 MB (overlays PO; PO dead
                                                                //        before O-proj writes Yw)
    int*   cisflag = (int*)(ws + (56u << 20));                  //  4 B
    u64*   mbits   = (u64*)(ws + (56u << 20) + 4096);           //  2 KB [4][64]
    u64*   cbits   = (u64*)(ws + (56u << 20) + 8192);           // 512 KB [1024][64]
    float* PL      = (float*)(ws + (56u << 20) + 544 * 1024);   // 512 KB [1024][128]

    detect_cis<<<1, 64, 0, stream>>>((const unsigned char*)cis, cisflag);
    pack_masks<<<(CIS_WORDS + BATCH * (S_LEN / 64) + 3) / 4, 256, 0, stream>>>(
        cis, mask, cisflag, cbits, mbits);

    // Q projection (pre-scaled by (1/sqrt(dk)) * log2(e) for exp2 softmax).
    gemm128<0, 0, 1024><<<dim3(32, 4), 256, 0, stream>>>(queries, wq_w, wq_b, dq, Qbf, 0.125f * 1.44269504f);
    // Combined K+V projections: one dispatch, gridDim.z=2 (K | V^T).
    gemm_kv128<<<dim3(128, 4, 2), 256, 0, stream>>>(keys_values, wk_w, wk_b, dk, wv_w, wv_b, Kbf, Vt);

    // Fused masked flash attention (4-way S-split, round-14 barrier rhythm, exp2)
    attn_kernel<<<1024, 256, 0, stream>>>(Qbf, Kbf, Vt, mbits, cbits, PO, PL);
    attn_merge<<<2048, 256, 0, stream>>>(PO, PL, AO);

    // Output projection (bf16 A) -> f32 scratch (overwrites PO, now dead)
    gemm128<1, 1, 1024><<<dim3(32, 4), 256, 0, stream>>>(AO, wo_w, wo_b, nullptr, Yw, 1.0f);

    // LayerNorm -> d_out
    out_ln<<<4096, 256, 0, stream>>>(Yw, ln_g, ln_b, out);
}

// Round 17
// 208.341 us; speedup vs baseline: 1.0872x; 1.0556x over previous
//
#include <hip/hip_runtime.h>
#include <stdint.h>
#include <stddef.h>

typedef __bf16 bf16;
typedef __bf16 bf16x4 __attribute__((ext_vector_type(4)));
typedef __bf16 bf16x8 __attribute__((ext_vector_type(8)));
typedef float f32x4 __attribute__((ext_vector_type(4)));
typedef float f32x16 __attribute__((ext_vector_type(16)));
typedef unsigned long long u64;

#define BATCH 4
#define G_LEN 1024
#define S_LEN 4096
#define DM 512
#define NH 8
#define DK 64
#define CIS_WORDS (G_LEN * (S_LEN / 64))   // 65536

__device__ __forceinline__ f32x4 mfma16(bf16x8 a, bf16x8 b, f32x4 c) {
    return __builtin_amdgcn_mfma_f32_16x16x32_bf16(a, b, c, 0, 0, 0);
}
__device__ __forceinline__ f32x16 mfma32(bf16x8 a, bf16x8 b, f32x16 c) {
    return __builtin_amdgcn_mfma_f32_32x32x16_bf16(a, b, c, 0, 0, 0);
}
// v_cvt_pk_bf16_f32: dst.lo = bf16(lo), dst.hi = bf16(hi). No builtin (m240).
__device__ __forceinline__ uint32_t cvtpk(float lo, float hi_) {
    uint32_t r;
    asm("v_cvt_pk_bf16_f32 %0, %1, %2" : "=v"(r) : "v"(lo), "v"(hi_));
    return r;
}
// v_permlane32_swap_b32: a.lanes[32:64] <-> b.lanes[0:32] (gfx950).
__device__ __forceinline__ void pswap(uint32_t& a, uint32_t& b) {
    asm("v_permlane32_swap_b32 %0, %1" : "+v"(a), "+v"(b));
}
// raw v_exp_f32 (= exp2). OCML exp2f adds denorm-handling ops (round-16
// post-mortem: VALUBusy 52->58.6%, attn 84->99us). Underflow->0 is exactly
// what masked/negative scores want; no libcall, single transcendental op.
__device__ __forceinline__ float fexp2(float x) {
    float r;
    asm("v_exp_f32 %0, %1" : "=v"(r) : "v"(x));
    return r;
}
__device__ __forceinline__ bf16x8 mk8(uint32_t a, uint32_t b, uint32_t c, uint32_t d) {
    union { uint32_t u[4]; bf16x8 v; } x;
    x.u[0] = a; x.u[1] = b; x.u[2] = c; x.u[3] = d;
    return x.v;
}
// masked exp2 + bf16 pack + permlane redistribute into PV A-fragments.
// Scores arrive pre-scaled by 0.125*log2(e) (folded into Q projection).
__device__ __forceinline__ void exppack(f32x16& c, uint32_t kw, float& lsum,
                                        bf16x8& pa0, bf16x8& pa1) {
    #pragma unroll
    for (int reg = 0; reg < 16; ++reg) {
        const int bit = (reg & 3) + 8 * (reg >> 2);
        const float e = fexp2(c[reg]);
        c[reg] = ((kw >> bit) & 1u) ? e : 0.f;
    }
    lsum += ((c[0] + c[1]) + (c[2] + c[3])) + ((c[4] + c[5]) + (c[6] + c[7]))
          + ((c[8] + c[9]) + (c[10] + c[11])) + ((c[12] + c[13]) + (c[14] + c[15]));
    uint32_t wa0 = cvtpk(c[0],  c[1]),  wa1 = cvtpk(c[2],  c[3]);
    uint32_t wb0 = cvtpk(c[4],  c[5]),  wb1 = cvtpk(c[6],  c[7]);
    uint32_t wc0 = cvtpk(c[8],  c[9]),  wc1 = cvtpk(c[10], c[11]);
    uint32_t wd0 = cvtpk(c[12], c[13]), wd1 = cvtpk(c[14], c[15]);
    pswap(wa0, wb0); pswap(wa1, wb1); pswap(wc0, wd0); pswap(wc1, wd1);
    pa0 = mk8(wa0, wa1, wb0, wb1);   // s = 8hi + 0..7
    pa1 = mk8(wc0, wc1, wd0, wd1);   // s = 16 + 8hi + 0..7
}
// async global->LDS, 16B/lane. LDS dest is WAVE-UNIFORM base (HW adds lane*16).
__device__ __forceinline__ void stage16(const bf16* g, char* l) {
    __builtin_amdgcn_global_load_lds(
        (const __attribute__((address_space(1))) void*)g,
        (__attribute__((address_space(3))) void*)l, 16, 0, 0);
}

// ---------------------------------------------------------------------------
// cis dtype detection (bool vs int32) — see round 1 notes. flag=1 -> bytes.
// ---------------------------------------------------------------------------
__global__ void detect_cis(const unsigned char* __restrict__ cis, int* __restrict__ flag) {
    int any = 0;
    for (int i = threadIdx.x; i < 16384; i += 64)
        any |= cis[4 * i + 1];
    #pragma unroll
    for (int off = 1; off < 64; off <<= 1) any |= __shfl_xor(any, off);
    if (threadIdx.x == 0) flag[0] = (any != 0) ? 1 : 0;
}

// ---------------------------------------------------------------------------
// Pack cis[g][s] and mask[b][s] into bit-words (one wave per u64 via ballot).
// ---------------------------------------------------------------------------
__global__ __launch_bounds__(256) void pack_masks(
    const void* __restrict__ cisv, const int* __restrict__ mask,
    const int* __restrict__ flag, u64* __restrict__ cbits, u64* __restrict__ mbits)
{
    const int wid  = blockIdx.x * 4 + (threadIdx.x >> 6);
    const int lane = threadIdx.x & 63;
    if (wid < CIS_WORDS) {
        int v;
        if (flag[0]) v = ((const unsigned char*)cisv)[(size_t)wid * 64 + lane];
        else         v = ((const int*)cisv)[(size_t)wid * 64 + lane];
        const u64 bits = __ballot(v != 0);
        if (lane == 0) cbits[wid] = bits;
    } else if (wid < CIS_WORDS + BATCH * (S_LEN / 64)) {
        const int w2 = wid - CIS_WORDS;               // b*64 + sw
        const u64 bits = __ballot(mask[w2 * 64 + lane] != 0);
        if (lane == 0) mbits[w2] = bits;
    }
}

// ---------------------------------------------------------------------------
// 64x64-tile GEMM for the SMALL projections (Q, O): M=4096 -> 512 blocks =
// 2 blocks/CU (the 128-tile version left half the CUs idle: 128 blocks).
// Round-2-proven fragment paths; LDS stride 72 (2-way aliasing is free).
// ---------------------------------------------------------------------------
template<int A_IS_BF16, int OUT_F32, int ROWS_PER_B>
__global__ __launch_bounds__(256) void gemm64(
    const void* __restrict__ Ap, const float* __restrict__ W,
    const float* __restrict__ bias, const float* __restrict__ shift,
    void* __restrict__ Out, float oscale)
{
    __shared__ bf16 As[64][72];
    __shared__ bf16 Bs[64][72];
    const int tid  = threadIdx.x;
    const int lane = tid & 63;
    const int wave = tid >> 6;
    const int l15  = lane & 15;
    const int l4   = lane >> 4;
    const int m0   = blockIdx.x * 64;
    const int n0   = blockIdx.y * 64;

    f32x4 acc[4] = {};

    for (int kt = 0; kt < DM; kt += 64) {
        #pragma unroll
        for (int i = 0; i < 4; ++i) {
            const int q   = tid + i * 256;
            const int row = q >> 4;
            const int kq  = (q & 15) * 4;
            bf16x4 av;
            if (A_IS_BF16) {
                av = *(const bf16x4*)((const bf16*)Ap + (size_t)(m0 + row) * DM + kt + kq);
            } else {
                const float4 v = *(const float4*)((const float*)Ap + (size_t)(m0 + row) * DM + kt + kq);
                av[0] = (bf16)v.x; av[1] = (bf16)v.y; av[2] = (bf16)v.z; av[3] = (bf16)v.w;
            }
            *(bf16x4*)&As[row][kq] = av;
            const float4 w = *(const float4*)(W + (size_t)(n0 + row) * DM + kt + kq);
            bf16x4 bv;
            bv[0] = (bf16)w.x; bv[1] = (bf16)w.y; bv[2] = (bf16)w.z; bv[3] = (bf16)w.w;
            *(bf16x4*)&Bs[row][kq] = bv;
        }
        __syncthreads();
        #pragma unroll
        for (int ks = 0; ks < 64; ks += 32) {
            const bf16x8 a = *(const bf16x8*)&As[wave * 16 + l15][ks + 8 * l4];
            #pragma unroll
            for (int n = 0; n < 4; ++n) {
                const bf16x8 b = *(const bf16x8*)&Bs[n * 16 + l15][ks + 8 * l4];
                acc[n] = mfma16(a, b, acc[n]);
            }
        }
        __syncthreads();
    }

    #pragma unroll
    for (int n = 0; n < 4; ++n) {
        const int col = n0 + n * 16 + l15;
        const float bv = bias[col];
        #pragma unroll
        for (int r = 0; r < 4; ++r) {
            const int m = m0 + wave * 16 + l4 * 4 + r;
            float v = acc[n][r] + bv;
            if (shift) v += shift[(m / ROWS_PER_B) * DM + col];
            v *= oscale;
            if (OUT_F32) ((float*)Out)[(size_t)m * DM + col] = v;
            else         ((bf16*)Out)[(size_t)m * DM + col] = (bf16)v;
        }
    }
}

// ---------------------------------------------------------------------------
// Combined K+V projection in ONE dispatch (round-16, proven: non-attn -9us):
// gridDim.z = 2 (z=0: K with +dk shift; z=1: V transposed). 128x128 tiles.
// ---------------------------------------------------------------------------
__global__ __launch_bounds__(256) void gemm_kv128(
    const float* __restrict__ X,
    const float* __restrict__ Wk, const float* __restrict__ bk, const float* __restrict__ dkv,
    const float* __restrict__ Wv, const float* __restrict__ bv,
    bf16* __restrict__ OutK, bf16* __restrict__ OutVt)
{
    __shared__ bf16 As[128][72];
    __shared__ bf16 Bs[128][72];
    const int tid  = threadIdx.x;
    const int lane = tid & 63;
    const int wave = tid >> 6;
    const int l15  = lane & 15;
    const int l4   = lane >> 4;
    const int wr   = wave >> 1;
    const int wc   = wave & 1;
    const int m0   = blockIdx.x * 128;
    const int n0   = blockIdx.y * 128;
    const int isV  = blockIdx.z;
    const float* W = isV ? Wv : Wk;

    f32x4 acc[4][4] = {};

    for (int kt = 0; kt < DM; kt += 64) {
        #pragma unroll
        for (int i = 0; i < 8; ++i) {
            const int q   = tid + i * 256;
            const int row = q >> 4;
            const int kq  = (q & 15) * 4;
            const float4 x = *(const float4*)(X + (size_t)(m0 + row) * DM + kt + kq);
            bf16x4 av;
            av[0] = (bf16)x.x; av[1] = (bf16)x.y; av[2] = (bf16)x.z; av[3] = (bf16)x.w;
            *(bf16x4*)&As[row][kq] = av;
            const float4 w = *(const float4*)(W + (size_t)(n0 + row) * DM + kt + kq);
            bf16x4 bvv;
            bvv[0] = (bf16)w.x; bvv[1] = (bf16)w.y; bvv[2] = (bf16)w.z; bvv[3] = (bf16)w.w;
            *(bf16x4*)&Bs[row][kq] = bvv;
        }
        __syncthreads();
        #pragma unroll
        for (int ks = 0; ks < 64; ks += 32) {
            bf16x8 af[4];
            #pragma unroll
            for (int mi = 0; mi < 4; ++mi)
                af[mi] = *(const bf16x8*)&As[wr * 64 + mi * 16 + l15][ks + 8 * l4];
            #pragma unroll
            for (int n = 0; n < 4; ++n) {
                const bf16x8 b = *(const bf16x8*)&Bs[wc * 64 + n * 16 + l15][ks + 8 * l4];
                #pragma unroll
                for (int mi = 0; mi < 4; ++mi)
                    acc[mi][n] = mfma16(af[mi], b, acc[mi][n]);
            }
        }
        __syncthreads();
    }

    #pragma unroll
    for (int n = 0; n < 4; ++n) {
        const int col = n0 + wc * 64 + n * 16 + l15;
        const float bkc = bk[col];
        const float bvc = bv[col];
        #pragma unroll
        for (int mi = 0; mi < 4; ++mi) {
            const int mb = m0 + wr * 64 + mi * 16 + l4 * 4;   // 4-aligned
            const int bb = mb >> 12;                          // batch = m / 4096
            if (isV) {
                bf16x4 o;
                #pragma unroll
                for (int r = 0; r < 4; ++r) o[r] = (bf16)(acc[mi][n][r] + bvc);
                *(bf16x4*)(OutVt + ((size_t)bb * DM + col) * 4096 + (mb & 4095)) = o;
            } else {
                const float sh = dkv[bb * DM + col];
                #pragma unroll
                for (int r = 0; r < 4; ++r)
                    OutK[(size_t)(mb + r) * DM + col] = (bf16)(acc[mi][n][r] + bkc + sh);
            }
        }
    }
}

// ---------------------------------------------------------------------------
// Flash attention v4c: round-14 structure (proven 84us) + raw-v_exp exp2.
// 4-way S-split, grid 1024; LDS 2x16KB dbuf; two barriers per tile with
// vmcnt(4) AFTER the next-tile STAGE issue (round-15 lesson).
// ---------------------------------------------------------------------------
__global__ __launch_bounds__(256) void attn_kernel(
    const bf16* __restrict__ Qb, const bf16* __restrict__ Kb,
    const bf16* __restrict__ Vt, const u64* __restrict__ mbits,
    const u64* __restrict__ cbits, bf16* __restrict__ PO, float* __restrict__ PL)
{
    __shared__ __align__(16) char sm[32768];   // 2 x (8KB K | 8KB V)

    const int tid  = threadIdx.x;
    const int lane = tid & 63;
    const int wave = tid >> 6;
    const int l31  = lane & 31;
    const int hi   = lane >> 5;

    // 1024 blocks = 8 XCD x 4 pairs x (8 g-tiles x 4 S-quarters).
    const int flat = blockIdx.x;
    const int xcd  = flat & 7;
    const int slot = flat >> 3;               // 0..127
    const int pr   = xcd * 4 + (slot >> 5);   // (b,h) pair 0..31
    const int sub  = slot & 31;               // gt*4 + squarter
    const int b    = pr >> 3;
    const int h    = pr & 7;
    const int g0   = (sub >> 2) * 128;
    const int tb   = (sub & 3) * 16;          // tile base (S-quarter, 16 tiles)
    const int blkid = pr * 32 + sub;          // scratch slot 0..1023

    // Q B-frags: q = g0 + wave*32 + l31 (Q pre-scaled 0.125*log2e)
    const bf16* qbase = Qb + (size_t)(b * G_LEN + g0 + wave * 32 + l31) * DM + h * DK + 8 * hi;
    const bf16x8 qf0 = *(const bf16x8*)(qbase);
    const bf16x8 qf1 = *(const bf16x8*)(qbase + 16);
    const bf16x8 qf2 = *(const bf16x8*)(qbase + 32);
    const bf16x8 qf3 = *(const bf16x8*)(qbase + 48);

    const bf16* Kh = Kb + (size_t)b * S_LEN * DM + h * DK;
    const bf16* Vh = Vt + (size_t)(b * NH + h) * DK * S_LEN;
    const u64*  mbv = mbits + b * (S_LEN / 64);
    const u64*  cbv = cbits + (size_t)(g0 + wave * 32 + l31) * (S_LEN / 64);

    // Staging: waves 0,1 stage K rows, waves 2,3 stage V rows.
    // lds off = wave*4096 + i*1024 + lane*16 -> row=(wave&1)*32+i*8+(lane>>3),
    // col16=lane&7. Source pre-swizzle col16s = (lane&7)^(row&7) (rule 21).
    const bool isK    = (wave < 2);
    const int rowbase = (wave & 1) * 32 + (lane >> 3);
    const int col16s  = (lane & 7) ^ (rowbase & 7);
    const int swz     = l31 & 7;   // read-side swizzle key

#define STAGE(tt, bufi) do {                                                   \
    char* ldw = sm + (bufi) * 16384 + wave * 4096;                             \
    _Pragma("unroll")                                                          \
    for (int i = 0; i < 4; ++i) {                                              \
        const int row = rowbase + i * 8;                                       \
        const bf16* g = isK                                                    \
            ? (Kh + (size_t)((tt) * 64 + row) * DM + col16s * 8)               \
            : (Vh + (size_t)row * S_LEN + (tt) * 64 + col16s * 8);             \
        stage16(g, ldw + i * 1024);                                            \
    }                                                                          \
} while (0)

    f32x16 accA = {};   // d = l31
    f32x16 accB = {};   // d = 32 + l31
    float lsum = 0.f;

    // prologue: tile tb in flight
    STAGE(tb + 0, 0);

    for (int t = 0; t < 16; ++t) {
        __builtin_amdgcn_s_barrier();              // all waves done reading buf[(t+1)&1]
        __builtin_amdgcn_sched_barrier(0);
        if (t + 1 < 16) {
            STAGE(tb + t + 1, (t + 1) & 1);
            asm volatile("s_waitcnt vmcnt(4)" ::: "memory");   // tile t staged; t+1 in flight
        } else {
            asm volatile("s_waitcnt vmcnt(0)" ::: "memory");
        }
        __builtin_amdgcn_s_barrier();              // buf[t&1] staged for all waves
        __builtin_amdgcn_sched_barrier(0);

        const char* bK = sm + (t & 1) * 16384;
        const char* bV = bK + 8192;

        // ---- QK^T (A = K from LDS, swizzled read): D[s_sub][q]
#define KF(ss, m) (*(const bf16x8*)(bK + ((ss) * 32 + l31) * 128 + (((2 * (m) + hi) ^ swz) * 16)))
        f32x16 c0 = {}, c1 = {};
        c0 = mfma32(KF(0, 0), qf0, c0); c0 = mfma32(KF(0, 1), qf1, c0);
        c0 = mfma32(KF(0, 2), qf2, c0); c0 = mfma32(KF(0, 3), qf3, c0);
        c1 = mfma32(KF(1, 0), qf0, c1); c1 = mfma32(KF(1, 1), qf1, c1);
        c1 = mfma32(KF(1, 2), qf2, c1); c1 = mfma32(KF(1, 3), qf3, c1);

        // ---- masks: one u64 per 64-s tile
        const u64 w64 = cbv[tb + t] & mbv[tb + t];
        const uint32_t kw0 = ((uint32_t)w64) >> (4 * hi);
        const uint32_t kw1 = ((uint32_t)(w64 >> 32)) >> (4 * hi);

        bf16x8 pa0, pa1, pb0, pb1;
        exppack(c0, kw0, lsum, pa0, pa1);
        exppack(c1, kw1, lsum, pb0, pb1);

        // ---- PV (B = V from LDS, swizzled read): acc[q][d]
#define VF(ss, ks, dh) (*(const bf16x8*)(bV + ((dh) * 32 + l31) * 128 + ((((ss) * 4 + (ks) * 2 + hi) ^ swz) * 16)))
        accA = mfma32(pa0, VF(0, 0, 0), accA); accA = mfma32(pa1, VF(0, 1, 0), accA);
        accA = mfma32(pb0, VF(1, 0, 0), accA); accA = mfma32(pb1, VF(1, 1, 0), accA);
        accB = mfma32(pa0, VF(0, 0, 1), accB); accB = mfma32(pa1, VF(0, 1, 1), accB);
        accB = mfma32(pb0, VF(1, 0, 1), accB); accB = mfma32(pb1, VF(1, 1, 1), accB);
    }
#undef KF
#undef VF
#undef STAGE

    // ---- write partials ----
    const float tl = lsum + __shfl_xor(lsum, 32);
    if (hi == 0) PL[blkid * 128 + wave * 32 + l31] = tl;
    bf16* po = PO + (size_t)blkid * 8192 + (wave * 32) * 64;
    #pragma unroll
    for (int reg = 0; reg < 16; ++reg) {
        const int q = (reg & 3) + 8 * (reg >> 2) + 4 * hi;
        po[q * 64 + l31]      = (bf16)accA[reg];
        po[q * 64 + 32 + l31] = (bf16)accB[reg];
    }
}

// ---------------------------------------------------------------------------
// Merge the four S-quarter partials -> AO. 2M elements, 4 per thread.
// ---------------------------------------------------------------------------
__global__ __launch_bounds__(256) void attn_merge(
    const bf16* __restrict__ PO, const float* __restrict__ PL, bf16* __restrict__ AO)
{
    const int idx = (blockIdx.x * 256 + threadIdx.x) * 4;   // 4 consecutive d
    const int row = idx >> 9;          // 0..4095 = b*1024 + g
    const int col = idx & 511;         // h*64 + d
    const int h   = col >> 6;
    const int d   = col & 63;
    const int pr  = (row >> 10) * 8 + h;
    const int gt  = (row & 1023) >> 7;
    const int q   = row & 127;
    const int slot0 = pr * 32 + gt * 4;
    float num[4] = {0.f, 0.f, 0.f, 0.f};
    float pl = 0.f;
    #pragma unroll
    for (int s = 0; s < 4; ++s) {
        const bf16x4 n = *(const bf16x4*)(PO + (size_t)(slot0 + s) * 8192 + q * 64 + d);
        #pragma unroll
        for (int j = 0; j < 4; ++j) num[j] += (float)n[j];
        pl += PL[(slot0 + s) * 128 + q];
    }
    const float inv = pl > 0.f ? 1.f / pl : 0.f;
    bf16x4 o;
    #pragma unroll
    for (int j = 0; j < 4; ++j) o[j] = (bf16)(num[j] * inv);
    *(bf16x4*)(AO + (size_t)row * 512 + col) = o;
}

// ---------------------------------------------------------------------------
// Row LayerNorm: one block per row (512 cols), 256 threads.
// ---------------------------------------------------------------------------
__global__ __launch_bounds__(256) void out_ln(
    const float* __restrict__ Y, const float* __restrict__ gam,
    const float* __restrict__ bet, float* __restrict__ out)
{
    const int row = blockIdx.x;
    const int tid = threadIdx.x;
    const float x0 = Y[(size_t)row * DM + tid];
    const float x1 = Y[(size_t)row * DM + 256 + tid];
    float s  = x0 + x1;
    float sq = x0 * x0 + x1 * x1;
    #pragma unroll
    for (int off = 1; off < 64; off <<= 1) {
        s  += __shfl_xor(s, off);
        sq += __shfl_xor(sq, off);
    }
    __shared__ float ss[4], ssq[4];
    const int wave = tid >> 6;
    if ((tid & 63) == 0) { ss[wave] = s; ssq[wave] = sq; }
    __syncthreads();
    s  = ss[0] + ss[1] + ss[2] + ss[3];
    sq = ssq[0] + ssq[1] + ssq[2] + ssq[3];
    const float mu  = s * (1.f / 512.f);
    const float var = sq * (1.f / 512.f) - mu * mu;
    const float rs  = rsqrtf(var + 1e-5f);
    out[(size_t)row * DM + tid]       = (x0 - mu) * rs * gam[tid] + bet[tid];
    out[(size_t)row * DM + 256 + tid] = (x1 - mu) * rs * gam[tid + 256] + bet[tid + 256];
}

// ---------------------------------------------------------------------------
extern "C" void kernel_launch(void* const* d_in, const int* in_sizes, int n_in,
                              void* d_out, int out_size, void* d_ws, size_t ws_size,
                              hipStream_t stream) {
    const float* queries     = (const float*)d_in[0];   // [4,1024,512]
    const float* keys_values = (const float*)d_in[1];   // [4,4096,512]
    const float* dq          = (const float*)d_in[2];   // [4,1,512]
    const float* dk          = (const float*)d_in[3];   // [4,1,512]
    const int*   mask        = (const int*)d_in[4];     // [4,4096]
    const void*  cis         = d_in[5];                 // [1024,4096] bool (dtype detected)
    const float* wq_w = (const float*)d_in[6];
    const float* wq_b = (const float*)d_in[7];
    const float* wk_w = (const float*)d_in[8];
    const float* wk_b = (const float*)d_in[9];
    const float* wv_w = (const float*)d_in[10];
    const float* wv_b = (const float*)d_in[11];
    const float* wo_w = (const float*)d_in[12];
    const float* wo_b = (const float*)d_in[13];
    const float* ln_g = (const float*)d_in[14];
    const float* ln_b = (const float*)d_in[15];
    float* out = (float*)d_out;

    char* ws = (char*)d_ws;
    bf16*  Qbf = (bf16*)(ws);                                   //  4 MB (pre-scaled x0.125*log2e)
    bf16*  Kbf = (bf16*)(ws + (4u << 20));                      // 16 MB [16384,512]
    bf16*  Vt  = (bf16*)(ws + (20u << 20));                     // 16 MB [4,8,64,4096]
    bf16*  AO  = (bf16*)(ws + (36u << 20));                     //  4 MB [4096,512]
    bf16*  PO  = (bf16*)(ws + (40u << 20));                     // 16 MB partial numerators [1024][8192]
    float* Yw  = (float*)(ws + (40u << 20));                    //  8 MB (overlays PO; PO dead
                                                                //        before O-proj writes Yw)
    int*   cisflag = (int*)(ws + (56u << 20));                  //  4 B
    u64*   mbits   = (u64*)(ws + (56u << 20) + 4096);           //  2 KB [4][64]
    u64*   cbits   = (u64*)(ws + (56u << 20) + 8192);           // 512 KB [1024][64]
    float* PL      = (float*)(ws + (56u << 20) + 544 * 1024);   // 512 KB [1024][128]

    detect_cis<<<1, 64, 0, stream>>>((const unsigned char*)cis, cisflag);
    pack_masks<<<(CIS_WORDS + BATCH * (S_LEN / 64) + 3) / 4, 256, 0, stream>>>(
        cis, mask, cisflag, cbits, mbits);

    // Q projection (64-tile: 512 blocks; pre-scaled (1/sqrt(dk))*log2e for exp2).
    gemm64<0, 0, 1024><<<dim3(64, 8), 256, 0, stream>>>(queries, wq_w, wq_b, dq, Qbf, 0.125f * 1.44269504f);
    // Combined K+V projections: one dispatch, gridDim.z=2 (K | V^T), 128-tile.
    gemm_kv128<<<dim3(128, 4, 2), 256, 0, stream>>>(keys_values, wk_w, wk_b, dk, wv_w, wv_b, Kbf, Vt);

    // Fused masked flash attention (4-way S-split, round-14 rhythm, raw v_exp)
    attn_kernel<<<1024, 256, 0, stream>>>(Qbf, Kbf, Vt, mbits, cbits, PO, PL);
    attn_merge<<<2048, 256, 0, stream>>>(PO, PL, AO);

    // Output projection (64-tile, bf16 A) -> f32 scratch (overwrites PO, now dead)
    gemm64<1, 1, 1024><<<dim3(64, 8), 256, 0, stream>>>(AO, wo_w, wo_b, nullptr, Yw, 1.0f);

    // LayerNorm -> d_out
    out_ln<<<4096, 256, 0, stream>>>(Yw, ln_g, ln_b, out);
}

// Round 18
// 183.667 us; speedup vs baseline: 1.2333x; 1.1343x over previous
//
#include <hip/hip_runtime.h>
#include <stdint.h>
#include <stddef.h>

typedef __bf16 bf16;
typedef __bf16 bf16x4 __attribute__((ext_vector_type(4)));
typedef __bf16 bf16x8 __attribute__((ext_vector_type(8)));
typedef float f32x4 __attribute__((ext_vector_type(4)));
typedef float f32x16 __attribute__((ext_vector_type(16)));
typedef unsigned long long u64;

#define BATCH 4
#define G_LEN 1024
#define S_LEN 4096
#define DM 512
#define NH 8
#define DK 64
#define CIS_WORDS (G_LEN * (S_LEN / 64))   // 65536
#define NQ_EL  (BATCH * G_LEN * DM)        // 2,097,152
#define NKV_EL (BATCH * S_LEN * DM)        // 8,388,608
#define NW_EL  (DM * DM)                   // 262,144

__device__ __forceinline__ f32x4 mfma16(bf16x8 a, bf16x8 b, f32x4 c) {
    return __builtin_amdgcn_mfma_f32_16x16x32_bf16(a, b, c, 0, 0, 0);
}
__device__ __forceinline__ f32x16 mfma32(bf16x8 a, bf16x8 b, f32x16 c) {
    return __builtin_amdgcn_mfma_f32_32x32x16_bf16(a, b, c, 0, 0, 0);
}
// v_cvt_pk_bf16_f32: dst.lo = bf16(lo), dst.hi = bf16(hi). No builtin (m240).
__device__ __forceinline__ uint32_t cvtpk(float lo, float hi_) {
    uint32_t r;
    asm("v_cvt_pk_bf16_f32 %0, %1, %2" : "=v"(r) : "v"(lo), "v"(hi_));
    return r;
}
// v_permlane32_swap_b32: a.lanes[32:64] <-> b.lanes[0:32] (gfx950).
__device__ __forceinline__ void pswap(uint32_t& a, uint32_t& b) {
    asm("v_permlane32_swap_b32 %0, %1" : "+v"(a), "+v"(b));
}
// raw v_exp_f32 (= exp2). OCML exp2f adds denorm-handling ops (round-16
// post-mortem: attn 84->99us). Round-17: raw exp = 78us. Underflow->0 is
// exactly what masked/negative scores want.
__device__ __forceinline__ float fexp2(float x) {
    float r;
    asm("v_exp_f32 %0, %1" : "=v"(r) : "v"(x));
    return r;
}
__device__ __forceinline__ bf16x8 mk8(uint32_t a, uint32_t b, uint32_t c, uint32_t d) {
    union { uint32_t u[4]; bf16x8 v; } x;
    x.u[0] = a; x.u[1] = b; x.u[2] = c; x.u[3] = d;
    return x.v;
}
// masked exp2 + bf16 pack + permlane redistribute into PV A-fragments.
// Scores arrive pre-scaled by 0.125*log2(e) (folded into Q projection).
__device__ __forceinline__ void exppack(f32x16& c, uint32_t kw, float& lsum,
                                        bf16x8& pa0, bf16x8& pa1) {
    #pragma unroll
    for (int reg = 0; reg < 16; ++reg) {
        const int bit = (reg & 3) + 8 * (reg >> 2);
        const float e = fexp2(c[reg]);
        c[reg] = ((kw >> bit) & 1u) ? e : 0.f;
    }
    lsum += ((c[0] + c[1]) + (c[2] + c[3])) + ((c[4] + c[5]) + (c[6] + c[7]))
          + ((c[8] + c[9]) + (c[10] + c[11])) + ((c[12] + c[13]) + (c[14] + c[15]));
    uint32_t wa0 = cvtpk(c[0],  c[1]),  wa1 = cvtpk(c[2],  c[3]);
    uint32_t wb0 = cvtpk(c[4],  c[5]),  wb1 = cvtpk(c[6],  c[7]);
    uint32_t wc0 = cvtpk(c[8],  c[9]),  wc1 = cvtpk(c[10], c[11]);
    uint32_t wd0 = cvtpk(c[12], c[13]), wd1 = cvtpk(c[14], c[15]);
    pswap(wa0, wb0); pswap(wa1, wb1); pswap(wc0, wd0); pswap(wc1, wd1);
    pa0 = mk8(wa0, wa1, wb0, wb1);   // s = 8hi + 0..7
    pa1 = mk8(wc0, wc1, wd0, wd1);   // s = 16 + 8hi + 0..7
}
// async global->LDS, 16B/lane. LDS dest is WAVE-UNIFORM base (HW adds lane*16).
__device__ __forceinline__ void stage16(const bf16* g, char* l) {
    __builtin_amdgcn_global_load_lds(
        (const __attribute__((address_space(1))) void*)g,
        (__attribute__((address_space(3))) void*)l, 16, 0, 0);
}

// ---------------------------------------------------------------------------
// cis dtype detection (bool vs int32) — see round 1 notes. flag=1 -> bytes.
// ---------------------------------------------------------------------------
__global__ void detect_cis(const unsigned char* __restrict__ cis, int* __restrict__ flag) {
    int any = 0;
    for (int i = threadIdx.x; i < 16384; i += 64)
        any |= cis[4 * i + 1];
    #pragma unroll
    for (int off = 1; off < 64; off <<= 1) any |= __shfl_xor(any, off);
    if (threadIdx.x == 0) flag[0] = (any != 0) ? 1 : 0;
}

// ---------------------------------------------------------------------------
// Pack cis[g][s] and mask[b][s] into bit-words (one wave per u64 via ballot).
// ---------------------------------------------------------------------------
__global__ __launch_bounds__(256) void pack_masks(
    const void* __restrict__ cisv, const int* __restrict__ mask,
    const int* __restrict__ flag, u64* __restrict__ cbits, u64* __restrict__ mbits)
{
    const int wid  = blockIdx.x * 4 + (threadIdx.x >> 6);
    const int lane = threadIdx.x & 63;
    if (wid < CIS_WORDS) {
        int v;
        if (flag[0]) v = ((const unsigned char*)cisv)[(size_t)wid * 64 + lane];
        else         v = ((const int*)cisv)[(size_t)wid * 64 + lane];
        const u64 bits = __ballot(v != 0);
        if (lane == 0) cbits[wid] = bits;
    } else if (wid < CIS_WORDS + BATCH * (S_LEN / 64)) {
        const int w2 = wid - CIS_WORDS;               // b*64 + sw
        const u64 bits = __ballot(mask[w2 * 64 + lane] != 0);
        if (lane == 0) mbits[w2] = bits;
    }
}

// ---------------------------------------------------------------------------
// Pre-convert all f32 GEMM operands to bf16 ONCE (round-18 lever): the GEMMs
// were re-reading f32 and re-converting per tile-visit (KV A: 256MB f32 + 2x
// cvt passes). Segments are 2048-element aligned -> every block wave-uniform.
// ---------------------------------------------------------------------------
__global__ __launch_bounds__(256) void cvt_all(
    const float* __restrict__ q, const float* __restrict__ kv,
    const float* __restrict__ wq, const float* __restrict__ wk,
    const float* __restrict__ wv, const float* __restrict__ wo,
    bf16* __restrict__ oq, bf16* __restrict__ okv, bf16* __restrict__ ow4)
{
    const size_t e = ((size_t)blockIdx.x * 256 + threadIdx.x) * 8;
    const float* src;
    bf16* dst;
    size_t off;
    if (e < NQ_EL)               { src = q;  dst = oq;  off = e; }
    else if (e < NQ_EL + NKV_EL) { src = kv; dst = okv; off = e - NQ_EL; }
    else {
        const size_t w = e - NQ_EL - NKV_EL;
        const int wi = (int)(w / NW_EL);
        off = w % NW_EL;
        src = (wi == 0) ? wq : (wi == 1) ? wk : (wi == 2) ? wv : wo;
        dst = ow4 + (size_t)wi * NW_EL;
    }
    const float4 a = *(const float4*)(src + off);
    const float4 b = *(const float4*)(src + off + 4);
    bf16x8 o;
    o[0] = (bf16)a.x; o[1] = (bf16)a.y; o[2] = (bf16)a.z; o[3] = (bf16)a.w;
    o[4] = (bf16)b.x; o[5] = (bf16)b.y; o[6] = (bf16)b.z; o[7] = (bf16)b.w;
    *(bf16x8*)(dst + off) = o;
}

// ---------------------------------------------------------------------------
// All-bf16 64x64-tile GEMM (Q-proj, O-proj): 512 blocks = 2/CU. Staging is a
// pure bf16x8 copy (2 iters, no cvt). LDS stride 72 (2-way aliasing free).
// ---------------------------------------------------------------------------
template<int OUT_F32, int ROWS_PER_B>
__global__ __launch_bounds__(256) void gemm64(
    const bf16* __restrict__ A, const bf16* __restrict__ B,
    const float* __restrict__ bias, const float* __restrict__ shift,
    void* __restrict__ Out, float oscale)
{
    __shared__ bf16 As[64][72];
    __shared__ bf16 Bs[64][72];
    const int tid  = threadIdx.x;
    const int lane = tid & 63;
    const int wave = tid >> 6;
    const int l15  = lane & 15;
    const int l4   = lane >> 4;
    const int m0   = blockIdx.x * 64;
    const int n0   = blockIdx.y * 64;

    f32x4 acc[4] = {};

    for (int kt = 0; kt < DM; kt += 64) {
        #pragma unroll
        for (int i = 0; i < 2; ++i) {
            const int q   = tid + i * 256;
            const int row = q >> 3;
            const int kq  = (q & 7) * 8;
            *(bf16x8*)&As[row][kq] = *(const bf16x8*)(A + (size_t)(m0 + row) * DM + kt + kq);
            *(bf16x8*)&Bs[row][kq] = *(const bf16x8*)(B + (size_t)(n0 + row) * DM + kt + kq);
        }
        __syncthreads();
        #pragma unroll
        for (int ks = 0; ks < 64; ks += 32) {
            const bf16x8 a = *(const bf16x8*)&As[wave * 16 + l15][ks + 8 * l4];
            #pragma unroll
            for (int n = 0; n < 4; ++n) {
                const bf16x8 b = *(const bf16x8*)&Bs[n * 16 + l15][ks + 8 * l4];
                acc[n] = mfma16(a, b, acc[n]);
            }
        }
        __syncthreads();
    }

    #pragma unroll
    for (int n = 0; n < 4; ++n) {
        const int col = n0 + n * 16 + l15;
        const float bv = bias[col];
        #pragma unroll
        for (int r = 0; r < 4; ++r) {
            const int m = m0 + wave * 16 + l4 * 4 + r;
            float v = acc[n][r] + bv;
            if (shift) v += shift[(m / ROWS_PER_B) * DM + col];
            v *= oscale;
            if (OUT_F32) ((float*)Out)[(size_t)m * DM + col] = v;
            else         ((bf16*)Out)[(size_t)m * DM + col] = (bf16)v;
        }
    }
}

// ---------------------------------------------------------------------------
// All-bf16 combined K+V projection, 128x128 tiles, gridDim.z = 2
// (z=0: K with +dk shift; z=1: V transposed).
// ---------------------------------------------------------------------------
__global__ __launch_bounds__(256) void gemm_kv128(
    const bf16* __restrict__ X,
    const bf16* __restrict__ Wk, const float* __restrict__ bk, const float* __restrict__ dkv,
    const bf16* __restrict__ Wv, const float* __restrict__ bv,
    bf16* __restrict__ OutK, bf16* __restrict__ OutVt)
{
    __shared__ bf16 As[128][72];
    __shared__ bf16 Bs[128][72];
    const int tid  = threadIdx.x;
    const int lane = tid & 63;
    const int wave = tid >> 6;
    const int l15  = lane & 15;
    const int l4   = lane >> 4;
    const int wr   = wave >> 1;
    const int wc   = wave & 1;
    const int m0   = blockIdx.x * 128;
    const int n0   = blockIdx.y * 128;
    const int isV  = blockIdx.z;
    const bf16* W  = isV ? Wv : Wk;

    f32x4 acc[4][4] = {};

    for (int kt = 0; kt < DM; kt += 64) {
        #pragma unroll
        for (int i = 0; i < 4; ++i) {
            const int q   = tid + i * 256;     // 0..1023
            const int row = q >> 3;            // 0..127
            const int kq  = (q & 7) * 8;       // 0..56
            *(bf16x8*)&As[row][kq] = *(const bf16x8*)(X + (size_t)(m0 + row) * DM + kt + kq);
            *(bf16x8*)&Bs[row][kq] = *(const bf16x8*)(W + (size_t)(n0 + row) * DM + kt + kq);
        }
        __syncthreads();
        #pragma unroll
        for (int ks = 0; ks < 64; ks += 32) {
            bf16x8 af[4];
            #pragma unroll
            for (int mi = 0; mi < 4; ++mi)
                af[mi] = *(const bf16x8*)&As[wr * 64 + mi * 16 + l15][ks + 8 * l4];
            #pragma unroll
            for (int n = 0; n < 4; ++n) {
                const bf16x8 b = *(const bf16x8*)&Bs[wc * 64 + n * 16 + l15][ks + 8 * l4];
                #pragma unroll
                for (int mi = 0; mi < 4; ++mi)
                    acc[mi][n] = mfma16(af[mi], b, acc[mi][n]);
            }
        }
        __syncthreads();
    }

    #pragma unroll
    for (int n = 0; n < 4; ++n) {
        const int col = n0 + wc * 64 + n * 16 + l15;
        const float bkc = bk[col];
        const float bvc = bv[col];
        #pragma unroll
        for (int mi = 0; mi < 4; ++mi) {
            const int mb = m0 + wr * 64 + mi * 16 + l4 * 4;   // 4-aligned
            const int bb = mb >> 12;                          // batch = m / 4096
            if (isV) {
                bf16x4 o;
                #pragma unroll
                for (int r = 0; r < 4; ++r) o[r] = (bf16)(acc[mi][n][r] + bvc);
                *(bf16x4*)(OutVt + ((size_t)bb * DM + col) * 4096 + (mb & 4095)) = o;
            } else {
                const float sh = dkv[bb * DM + col];
                #pragma unroll
                for (int r = 0; r < 4; ++r)
                    OutK[(size_t)(mb + r) * DM + col] = (bf16)(acc[mi][n][r] + bkc + sh);
            }
        }
    }
}

// ---------------------------------------------------------------------------
// Flash attention v4c (round-17, proven 78us): 4-way S-split, grid 1024;
// LDS 2x16KB dbuf; two barriers per tile with vmcnt(4) AFTER the next-tile
// STAGE issue; raw-v_exp exp2 softmax. UNCHANGED.
// ---------------------------------------------------------------------------
__global__ __launch_bounds__(256) void attn_kernel(
    const bf16* __restrict__ Qb, const bf16* __restrict__ Kb,
    const bf16* __restrict__ Vt, const u64* __restrict__ mbits,
    const u64* __restrict__ cbits, bf16* __restrict__ PO, float* __restrict__ PL)
{
    __shared__ __align__(16) char sm[32768];   // 2 x (8KB K | 8KB V)

    const int tid  = threadIdx.x;
    const int lane = tid & 63;
    const int wave = tid >> 6;
    const int l31  = lane & 31;
    const int hi   = lane >> 5;

    // 1024 blocks = 8 XCD x 4 pairs x (8 g-tiles x 4 S-quarters).
    const int flat = blockIdx.x;
    const int xcd  = flat & 7;
    const int slot = flat >> 3;               // 0..127
    const int pr   = xcd * 4 + (slot >> 5);   // (b,h) pair 0..31
    const int sub  = slot & 31;               // gt*4 + squarter
    const int b    = pr >> 3;
    const int h    = pr & 7;
    const int g0   = (sub >> 2) * 128;
    const int tb   = (sub & 3) * 16;          // tile base (S-quarter, 16 tiles)
    const int blkid = pr * 32 + sub;          // scratch slot 0..1023

    // Q B-frags: q = g0 + wave*32 + l31 (Q pre-scaled 0.125*log2e)
    const bf16* qbase = Qb + (size_t)(b * G_LEN + g0 + wave * 32 + l31) * DM + h * DK + 8 * hi;
    const bf16x8 qf0 = *(const bf16x8*)(qbase);
    const bf16x8 qf1 = *(const bf16x8*)(qbase + 16);
    const bf16x8 qf2 = *(const bf16x8*)(qbase + 32);
    const bf16x8 qf3 = *(const bf16x8*)(qbase + 48);

    const bf16* Kh = Kb + (size_t)b * S_LEN * DM + h * DK;
    const bf16* Vh = Vt + (size_t)(b * NH + h) * DK * S_LEN;
    const u64*  mbv = mbits + b * (S_LEN / 64);
    const u64*  cbv = cbits + (size_t)(g0 + wave * 32 + l31) * (S_LEN / 64);

    // Staging: waves 0,1 stage K rows, waves 2,3 stage V rows.
    // lds off = wave*4096 + i*1024 + lane*16 -> row=(wave&1)*32+i*8+(lane>>3),
    // col16=lane&7. Source pre-swizzle col16s = (lane&7)^(row&7) (rule 21).
    const bool isK    = (wave < 2);
    const int rowbase = (wave & 1) * 32 + (lane >> 3);
    const int col16s  = (lane & 7) ^ (rowbase & 7);
    const int swz     = l31 & 7;   // read-side swizzle key

#define STAGE(tt, bufi) do {                                                   \
    char* ldw = sm + (bufi) * 16384 + wave * 4096;                             \
    _Pragma("unroll")                                                          \
    for (int i = 0; i < 4; ++i) {                                              \
        const int row = rowbase + i * 8;                                       \
        const bf16* g = isK                                                    \
            ? (Kh + (size_t)((tt) * 64 + row) * DM + col16s * 8)               \
            : (Vh + (size_t)row * S_LEN + (tt) * 64 + col16s * 8);             \
        stage16(g, ldw + i * 1024);                                            \
    }                                                                          \
} while (0)

    f32x16 accA = {};   // d = l31
    f32x16 accB = {};   // d = 32 + l31
    float lsum = 0.f;

    // prologue: tile tb in flight
    STAGE(tb + 0, 0);

    for (int t = 0; t < 16; ++t) {
        __builtin_amdgcn_s_barrier();              // all waves done reading buf[(t+1)&1]
        __builtin_amdgcn_sched_barrier(0);
        if (t + 1 < 16) {
            STAGE(tb + t + 1, (t + 1) & 1);
            asm volatile("s_waitcnt vmcnt(4)" ::: "memory");   // tile t staged; t+1 in flight
        } else {
            asm volatile("s_waitcnt vmcnt(0)" ::: "memory");
        }
        __builtin_amdgcn_s_barrier();              // buf[t&1] staged for all waves
        __builtin_amdgcn_sched_barrier(0);

        const char* bK = sm + (t & 1) * 16384;
        const char* bV = bK + 8192;

        // ---- QK^T (A = K from LDS, swizzled read): D[s_sub][q]
#define KF(ss, m) (*(const bf16x8*)(bK + ((ss) * 32 + l31) * 128 + (((2 * (m) + hi) ^ swz) * 16)))
        f32x16 c0 = {}, c1 = {};
        c0 = mfma32(KF(0, 0), qf0, c0); c0 = mfma32(KF(0, 1), qf1, c0);
        c0 = mfma32(KF(0, 2), qf2, c0); c0 = mfma32(KF(0, 3), qf3, c0);
        c1 = mfma32(KF(1, 0), qf0, c1); c1 = mfma32(KF(1, 1), qf1, c1);
        c1 = mfma32(KF(1, 2), qf2, c1); c1 = mfma32(KF(1, 3), qf3, c1);

        // ---- masks: one u64 per 64-s tile
        const u64 w64 = cbv[tb + t] & mbv[tb + t];
        const uint32_t kw0 = ((uint32_t)w64) >> (4 * hi);
        const uint32_t kw1 = ((uint32_t)(w64 >> 32)) >> (4 * hi);

        bf16x8 pa0, pa1, pb0, pb1;
        exppack(c0, kw0, lsum, pa0, pa1);
        exppack(c1, kw1, lsum, pb0, pb1);

        // ---- PV (B = V from LDS, swizzled read): acc[q][d]
#define VF(ss, ks, dh) (*(const bf16x8*)(bV + ((dh) * 32 + l31) * 128 + ((((ss) * 4 + (ks) * 2 + hi) ^ swz) * 16)))
        accA = mfma32(pa0, VF(0, 0, 0), accA); accA = mfma32(pa1, VF(0, 1, 0), accA);
        accA = mfma32(pb0, VF(1, 0, 0), accA); accA = mfma32(pb1, VF(1, 1, 0), accA);
        accB = mfma32(pa0, VF(0, 0, 1), accB); accB = mfma32(pa1, VF(0, 1, 1), accB);
        accB = mfma32(pb0, VF(1, 0, 1), accB); accB = mfma32(pb1, VF(1, 1, 1), accB);
    }
#undef KF
#undef VF
#undef STAGE

    // ---- write partials ----
    const float tl = lsum + __shfl_xor(lsum, 32);
    if (hi == 0) PL[blkid * 128 + wave * 32 + l31] = tl;
    bf16* po = PO + (size_t)blkid * 8192 + (wave * 32) * 64;
    #pragma unroll
    for (int reg = 0; reg < 16; ++reg) {
        const int q = (reg & 3) + 8 * (reg >> 2) + 4 * hi;
        po[q * 64 + l31]      = (bf16)accA[reg];
        po[q * 64 + 32 + l31] = (bf16)accB[reg];
    }
}

// ---------------------------------------------------------------------------
// Merge the four S-quarter partials -> AO. 2M elements, 4 per thread.
// ---------------------------------------------------------------------------
__global__ __launch_bounds__(256) void attn_merge(
    const bf16* __restrict__ PO, const float* __restrict__ PL, bf16* __restrict__ AO)
{
    const int idx = (blockIdx.x * 256 + threadIdx.x) * 4;   // 4 consecutive d
    const int row = idx >> 9;          // 0..4095 = b*1024 + g
    const int col = idx & 511;         // h*64 + d
    const int h   = col >> 6;
    const int d   = col & 63;
    const int pr  = (row >> 10) * 8 + h;
    const int gt  = (row & 1023) >> 7;
    const int q   = row & 127;
    const int slot0 = pr * 32 + gt * 4;
    float num[4] = {0.f, 0.f, 0.f, 0.f};
    float pl = 0.f;
    #pragma unroll
    for (int s = 0; s < 4; ++s) {
        const bf16x4 n = *(const bf16x4*)(PO + (size_t)(slot0 + s) * 8192 + q * 64 + d);
        #pragma unroll
        for (int j = 0; j < 4; ++j) num[j] += (float)n[j];
        pl += PL[(slot0 + s) * 128 + q];
    }
    const float inv = pl > 0.f ? 1.f / pl : 0.f;
    bf16x4 o;
    #pragma unroll
    for (int j = 0; j < 4; ++j) o[j] = (bf16)(num[j] * inv);
    *(bf16x4*)(AO + (size_t)row * 512 + col) = o;
}

// ---------------------------------------------------------------------------
// Row LayerNorm: one block per row (512 cols), 256 threads.
// ---------------------------------------------------------------------------
__global__ __launch_bounds__(256) void out_ln(
    const float* __restrict__ Y, const float* __restrict__ gam,
    const float* __restrict__ bet, float* __restrict__ out)
{
    const int row = blockIdx.x;
    const int tid = threadIdx.x;
    const float x0 = Y[(size_t)row * DM + tid];
    const float x1 = Y[(size_t)row * DM + 256 + tid];
    float s  = x0 + x1;
    float sq = x0 * x0 + x1 * x1;
    #pragma unroll
    for (int off = 1; off < 64; off <<= 1) {
        s  += __shfl_xor(s, off);
        sq += __shfl_xor(sq, off);
    }
    __shared__ float ss[4], ssq[4];
    const int wave = tid >> 6;
    if ((tid & 63) == 0) { ss[wave] = s; ssq[wave] = sq; }
    __syncthreads();
    s  = ss[0] + ss[1] + ss[2] + ss[3];
    sq = ssq[0] + ssq[1] + ssq[2] + ssq[3];
    const float mu  = s * (1.f / 512.f);
    const float var = sq * (1.f / 512.f) - mu * mu;
    const float rs  = rsqrtf(var + 1e-5f);
    out[(size_t)row * DM + tid]       = (x0 - mu) * rs * gam[tid] + bet[tid];
    out[(size_t)row * DM + 256 + tid] = (x1 - mu) * rs * gam[tid + 256] + bet[tid + 256];
}

// ---------------------------------------------------------------------------
extern "C" void kernel_launch(void* const* d_in, const int* in_sizes, int n_in,
                              void* d_out, int out_size, void* d_ws, size_t ws_size,
                              hipStream_t stream) {
    const float* queries     = (const float*)d_in[0];   // [4,1024,512]
    const float* keys_values = (const float*)d_in[1];   // [4,4096,512]
    const float* dq          = (const float*)d_in[2];   // [4,1,512]
    const float* dk          = (const float*)d_in[3];   // [4,1,512]
    const int*   mask        = (const int*)d_in[4];     // [4,4096]
    const void*  cis         = d_in[5];                 // [1024,4096] bool (dtype detected)
    const float* wq_w = (const float*)d_in[6];
    const float* wq_b = (const float*)d_in[7];
    const float* wk_w = (const float*)d_in[8];
    const float* wk_b = (const float*)d_in[9];
    const float* wv_w = (const float*)d_in[10];
    const float* wv_b = (const float*)d_in[11];
    const float* wo_w = (const float*)d_in[12];
    const float* wo_b = (const float*)d_in[13];
    const float* ln_g = (const float*)d_in[14];
    const float* ln_b = (const float*)d_in[15];
    float* out = (float*)d_out;

    char* ws = (char*)d_ws;
    bf16*  Qbf = (bf16*)(ws);                                   //  4 MB (pre-scaled x0.125*log2e)
    bf16*  Kbf = (bf16*)(ws + (4u << 20));                      // 16 MB [16384,512]
    bf16*  Vt  = (bf16*)(ws + (20u << 20));                     // 16 MB [4,8,64,4096]
    bf16*  AO  = (bf16*)(ws + (36u << 20));                     //  4 MB [4096,512]
    bf16*  Xq  = (bf16*)(ws + (36u << 20));                     //  4 MB (overlays AO; dead
                                                                //        before merge writes AO)
    bf16*  PO  = (bf16*)(ws + (40u << 20));                     // 16 MB partial numerators
    bf16*  Xkv = (bf16*)(ws + (40u << 20));                     // 16 MB (overlays PO; dead
                                                                //        before attn writes PO)
    float* Yw  = (float*)(ws + (40u << 20));                    //  8 MB (overlays PO; PO dead
                                                                //        before O-proj writes Yw)
    int*   cisflag = (int*)(ws + (56u << 20));                  //  4 B
    u64*   mbits   = (u64*)(ws + (56u << 20) + 4096);           //  2 KB [4][64]
    u64*   cbits   = (u64*)(ws + (56u << 20) + 8192);           // 512 KB [1024][64]
    float* PL      = (float*)(ws + (56u << 20) + 544 * 1024);   // 512 KB [1024][128]
    bf16*  Wb4     = (bf16*)(ws + (58u << 20));                 //  2 MB: wq|wk|wv|wo bf16
    bf16*  Wqb = Wb4;
    bf16*  Wkb = Wb4 + (size_t)NW_EL;
    bf16*  Wvb = Wb4 + (size_t)2 * NW_EL;
    bf16*  Wob = Wb4 + (size_t)3 * NW_EL;

    detect_cis<<<1, 64, 0, stream>>>((const unsigned char*)cis, cisflag);
    pack_masks<<<(CIS_WORDS + BATCH * (S_LEN / 64) + 3) / 4, 256, 0, stream>>>(
        cis, mask, cisflag, cbits, mbits);

    // Pre-convert all f32 GEMM operands to bf16 once (11.5M elems / 8 per thread).
    cvt_all<<<(NQ_EL + NKV_EL + 4 * NW_EL) / 2048, 256, 0, stream>>>(
        queries, keys_values, wq_w, wk_w, wv_w, wo_w, Xq, Xkv, Wb4);

    // Q projection (all-bf16 64-tile; pre-scaled (1/sqrt(dk))*log2e for exp2).
    gemm64<0, 1024><<<dim3(64, 8), 256, 0, stream>>>(Xq, Wqb, wq_b, dq, Qbf, 0.125f * 1.44269504f);
    // Combined K+V projections (all-bf16 128-tile, gridDim.z=2: K | V^T).
    gemm_kv128<<<dim3(128, 4, 2), 256, 0, stream>>>(Xkv, Wkb, wk_b, dk, Wvb, wv_b, Kbf, Vt);

    // Fused masked flash attention (4-way S-split, round-14 rhythm, raw v_exp)
    attn_kernel<<<1024, 256, 0, stream>>>(Qbf, Kbf, Vt, mbits, cbits, PO, PL);
    attn_merge<<<2048, 256, 0, stream>>>(PO, PL, AO);

    // Output projection (all-bf16 64-tile) -> f32 scratch (overwrites PO, now dead)
    gemm64<1, 1024><<<dim3(64, 8), 256, 0, stream>>>(AO, Wob, wo_b, nullptr, Yw, 1.0f);

    // LayerNorm -> d_out
    out_ln<<<4096, 256, 0, stream>>>(Yw, ln_g, ln_b, out);
}

// Round 19
// 138.755 us; speedup vs baseline: 1.6325x; 1.3237x over previous
//
#include <hip/hip_runtime.h>
#include <stdint.h>
#include <stddef.h>

typedef __bf16 bf16;
typedef __bf16 bf16x4 __attribute__((ext_vector_type(4)));
typedef __bf16 bf16x8 __attribute__((ext_vector_type(8)));
typedef float f32x4 __attribute__((ext_vector_type(4)));
typedef float f32x16 __attribute__((ext_vector_type(16)));
typedef unsigned long long u64;

#define BATCH 4
#define G_LEN 1024
#define S_LEN 4096
#define DM 512
#define NH 8
#define DK 64
#define CIS_WORDS (G_LEN * (S_LEN / 64))   // 65536
#define NQ_EL  (BATCH * G_LEN * DM)        // 2,097,152
#define NKV_EL (BATCH * S_LEN * DM)        // 8,388,608
#define NW_EL  (DM * DM)                   // 262,144
#define PACK_BLOCKS ((CIS_WORDS + BATCH * (S_LEN / 64) + 3) / 4)   // 16448
#define CVT_BLOCKS  ((NQ_EL + NKV_EL + 4 * NW_EL) / 2048)          // 5632
#define QSCALE (0.125f * 1.44269504f)

__device__ __forceinline__ f32x4 mfma16(bf16x8 a, bf16x8 b, f32x4 c) {
    return __builtin_amdgcn_mfma_f32_16x16x32_bf16(a, b, c, 0, 0, 0);
}
__device__ __forceinline__ f32x16 mfma32(bf16x8 a, bf16x8 b, f32x16 c) {
    return __builtin_amdgcn_mfma_f32_32x32x16_bf16(a, b, c, 0, 0, 0);
}
// v_cvt_pk_bf16_f32: dst.lo = bf16(lo), dst.hi = bf16(hi). No builtin (m240).
__device__ __forceinline__ uint32_t cvtpk(float lo, float hi_) {
    uint32_t r;
    asm("v_cvt_pk_bf16_f32 %0, %1, %2" : "=v"(r) : "v"(lo), "v"(hi_));
    return r;
}
// v_permlane32_swap_b32: a.lanes[32:64] <-> b.lanes[0:32] (gfx950).
__device__ __forceinline__ void pswap(uint32_t& a, uint32_t& b) {
    asm("v_permlane32_swap_b32 %0, %1" : "+v"(a), "+v"(b));
}
// raw v_exp_f32 (= exp2): round-17 proven (78us vs OCML exp2f's 99us).
__device__ __forceinline__ float fexp2(float x) {
    float r;
    asm("v_exp_f32 %0, %1" : "=v"(r) : "v"(x));
    return r;
}
__device__ __forceinline__ bf16x8 mk8(uint32_t a, uint32_t b, uint32_t c, uint32_t d) {
    union { uint32_t u[4]; bf16x8 v; } x;
    x.u[0] = a; x.u[1] = b; x.u[2] = c; x.u[3] = d;
    return x.v;
}
// masked exp2 + bf16 pack + permlane redistribute into PV A-fragments.
__device__ __forceinline__ void exppack(f32x16& c, uint32_t kw, float& lsum,
                                        bf16x8& pa0, bf16x8& pa1) {
    #pragma unroll
    for (int reg = 0; reg < 16; ++reg) {
        const int bit = (reg & 3) + 8 * (reg >> 2);
        const float e = fexp2(c[reg]);
        c[reg] = ((kw >> bit) & 1u) ? e : 0.f;
    }
    lsum += ((c[0] + c[1]) + (c[2] + c[3])) + ((c[4] + c[5]) + (c[6] + c[7]))
          + ((c[8] + c[9]) + (c[10] + c[11])) + ((c[12] + c[13]) + (c[14] + c[15]));
    uint32_t wa0 = cvtpk(c[0],  c[1]),  wa1 = cvtpk(c[2],  c[3]);
    uint32_t wb0 = cvtpk(c[4],  c[5]),  wb1 = cvtpk(c[6],  c[7]);
    uint32_t wc0 = cvtpk(c[8],  c[9]),  wc1 = cvtpk(c[10], c[11]);
    uint32_t wd0 = cvtpk(c[12], c[13]), wd1 = cvtpk(c[14], c[15]);
    pswap(wa0, wb0); pswap(wa1, wb1); pswap(wc0, wd0); pswap(wc1, wd1);
    pa0 = mk8(wa0, wa1, wb0, wb1);   // s = 8hi + 0..7
    pa1 = mk8(wc0, wc1, wd0, wd1);   // s = 16 + 8hi + 0..7
}
// async global->LDS, 16B/lane. LDS dest is WAVE-UNIFORM base (HW adds lane*16).
__device__ __forceinline__ void stage16(const bf16* g, char* l) {
    __builtin_amdgcn_global_load_lds(
        (const __attribute__((address_space(1))) void*)g,
        (__attribute__((address_space(3))) void*)l, 16, 0, 0);
}

// ---------------------------------------------------------------------------
// ONE prep dispatch (round-19): blocks [0, PACK_BLOCKS) pack cis+mask bits
// with INLINE dtype detection (wave samples bytes 4*lane+1 of the first 256B:
// int32 0/1 -> all zero; random bool -> nonzero w.p. 1-2^-64; L2-hot lines).
// Blocks [PACK_BLOCKS, +CVT_BLOCKS) convert f32 operands -> bf16 (8/thread).
// Replaces detect_cis + pack_masks + cvt_all (3 dispatches -> 1).
// ---------------------------------------------------------------------------
__global__ __launch_bounds__(256) void prep(
    const void* __restrict__ cisv, const int* __restrict__ mask,
    const float* __restrict__ q, const float* __restrict__ kv,
    const float* __restrict__ wq, const float* __restrict__ wk,
    const float* __restrict__ wv, const float* __restrict__ wo,
    u64* __restrict__ cbits, u64* __restrict__ mbits,
    bf16* __restrict__ oq, bf16* __restrict__ okv, bf16* __restrict__ ow4)
{
    const int bid = blockIdx.x;
    if (bid < PACK_BLOCKS) {
        const unsigned char* cis8 = (const unsigned char*)cisv;
        const int lane = threadIdx.x & 63;
        const int is_byte = __any((int)cis8[4 * lane + 1]);   // wave-uniform
        const int wid = bid * 4 + (threadIdx.x >> 6);
        if (wid < CIS_WORDS) {
            int v;
            if (is_byte) v = cis8[(size_t)wid * 64 + lane];
            else         v = ((const int*)cisv)[(size_t)wid * 64 + lane];
            const u64 bits = __ballot(v != 0);
            if (lane == 0) cbits[wid] = bits;
        } else if (wid < CIS_WORDS + BATCH * (S_LEN / 64)) {
            const int w2 = wid - CIS_WORDS;               // b*64 + sw
            const u64 bits = __ballot(mask[w2 * 64 + lane] != 0);
            if (lane == 0) mbits[w2] = bits;
        }
        return;
    }
    const size_t e = ((size_t)(bid - PACK_BLOCKS) * 256 + threadIdx.x) * 8;
    const float* src;
    bf16* dst;
    size_t off;
    if (e < NQ_EL)               { src = q;  dst = oq;  off = e; }
    else if (e < NQ_EL + NKV_EL) { src = kv; dst = okv; off = e - NQ_EL; }
    else {
        const size_t w = e - NQ_EL - NKV_EL;
        const int wi = (int)(w / NW_EL);
        off = w % NW_EL;
        src = (wi == 0) ? wq : (wi == 1) ? wk : (wi == 2) ? wv : wo;
        dst = ow4 + (size_t)wi * NW_EL;
    }
    const float4 a = *(const float4*)(src + off);
    const float4 b = *(const float4*)(src + off + 4);
    bf16x8 o;
    o[0] = (bf16)a.x; o[1] = (bf16)a.y; o[2] = (bf16)a.z; o[3] = (bf16)a.w;
    o[4] = (bf16)b.x; o[5] = (bf16)b.y; o[6] = (bf16)b.z; o[7] = (bf16)b.w;
    *(bf16x8*)(dst + off) = o;
}

// ---------------------------------------------------------------------------
// All-bf16 64x64-tile GEMM (O-proj): 512 blocks = 2/CU; pure bf16x8 staging.
// ---------------------------------------------------------------------------
template<int OUT_F32, int ROWS_PER_B>
__global__ __launch_bounds__(256) void gemm64(
    const bf16* __restrict__ A, const bf16* __restrict__ B,
    const float* __restrict__ bias, const float* __restrict__ shift,
    void* __restrict__ Out, float oscale)
{
    __shared__ bf16 As[64][72];
    __shared__ bf16 Bs[64][72];
    const int tid  = threadIdx.x;
    const int lane = tid & 63;
    const int wave = tid >> 6;
    const int l15  = lane & 15;
    const int l4   = lane >> 4;
    const int m0   = blockIdx.x * 64;
    const int n0   = blockIdx.y * 64;

    f32x4 acc[4] = {};

    for (int kt = 0; kt < DM; kt += 64) {
        #pragma unroll
        for (int i = 0; i < 2; ++i) {
            const int q   = tid + i * 256;
            const int row = q >> 3;
            const int kq  = (q & 7) * 8;
            *(bf16x8*)&As[row][kq] = *(const bf16x8*)(A + (size_t)(m0 + row) * DM + kt + kq);
            *(bf16x8*)&Bs[row][kq] = *(const bf16x8*)(B + (size_t)(n0 + row) * DM + kt + kq);
        }
        __syncthreads();
        #pragma unroll
        for (int ks = 0; ks < 64; ks += 32) {
            const bf16x8 a = *(const bf16x8*)&As[wave * 16 + l15][ks + 8 * l4];
            #pragma unroll
            for (int n = 0; n < 4; ++n) {
                const bf16x8 b = *(const bf16x8*)&Bs[n * 16 + l15][ks + 8 * l4];
                acc[n] = mfma16(a, b, acc[n]);
            }
        }
        __syncthreads();
    }

    #pragma unroll
    for (int n = 0; n < 4; ++n) {
        const int col = n0 + n * 16 + l15;
        const float bv = bias[col];
        #pragma unroll
        for (int r = 0; r < 4; ++r) {
            const int m = m0 + wave * 16 + l4 * 4 + r;
            float v = acc[n][r] + bv;
            if (shift) v += shift[(m / ROWS_PER_B) * DM + col];
            v *= oscale;
            if (OUT_F32) ((float*)Out)[(size_t)m * DM + col] = v;
            else         ((bf16*)Out)[(size_t)m * DM + col] = (bf16)v;
        }
    }
}

// ---------------------------------------------------------------------------
// Combined K+V+Q projections in ONE dispatch (round-19): gridDim.z = 3.
// z=0: K (+dk shift); z=1: V transposed; z=2: Q (x<32 active; +dq, *QSCALE,
// batch stride 1024). All-bf16 128x128 tiles — Q's solo low-fill time hides
// under the 1024 K/V blocks.
// ---------------------------------------------------------------------------
__global__ __launch_bounds__(256) void gemm_kvq128(
    const bf16* __restrict__ Xkv, const bf16* __restrict__ Xq,
    const bf16* __restrict__ Wk, const float* __restrict__ bk, const float* __restrict__ dkv,
    const bf16* __restrict__ Wv, const float* __restrict__ bv,
    const bf16* __restrict__ Wq, const float* __restrict__ bq, const float* __restrict__ dq,
    bf16* __restrict__ OutK, bf16* __restrict__ OutVt, bf16* __restrict__ OutQ)
{
    const int z = blockIdx.z;
    if (z == 2 && blockIdx.x >= 32) return;   // Q: M=4096 -> 32 x-tiles

    __shared__ bf16 As[128][72];
    __shared__ bf16 Bs[128][72];
    const int tid  = threadIdx.x;
    const int lane = tid & 63;
    const int wave = tid >> 6;
    const int l15  = lane & 15;
    const int l4   = lane >> 4;
    const int wr   = wave >> 1;
    const int wc   = wave & 1;
    const int m0   = blockIdx.x * 128;
    const int n0   = blockIdx.y * 128;
    const bf16* X = (z == 2) ? Xq : Xkv;
    const bf16* W = (z == 0) ? Wk : (z == 1) ? Wv : Wq;

    f32x4 acc[4][4] = {};

    for (int kt = 0; kt < DM; kt += 64) {
        #pragma unroll
        for (int i = 0; i < 4; ++i) {
            const int q   = tid + i * 256;     // 0..1023
            const int row = q >> 3;            // 0..127
            const int kq  = (q & 7) * 8;       // 0..56
            *(bf16x8*)&As[row][kq] = *(const bf16x8*)(X + (size_t)(m0 + row) * DM + kt + kq);
            *(bf16x8*)&Bs[row][kq] = *(const bf16x8*)(W + (size_t)(n0 + row) * DM + kt + kq);
        }
        __syncthreads();
        #pragma unroll
        for (int ks = 0; ks < 64; ks += 32) {
            bf16x8 af[4];
            #pragma unroll
            for (int mi = 0; mi < 4; ++mi)
                af[mi] = *(const bf16x8*)&As[wr * 64 + mi * 16 + l15][ks + 8 * l4];
            #pragma unroll
            for (int n = 0; n < 4; ++n) {
                const bf16x8 b = *(const bf16x8*)&Bs[wc * 64 + n * 16 + l15][ks + 8 * l4];
                #pragma unroll
                for (int mi = 0; mi < 4; ++mi)
                    acc[mi][n] = mfma16(af[mi], b, acc[mi][n]);
            }
        }
        __syncthreads();
    }

    #pragma unroll
    for (int n = 0; n < 4; ++n) {
        const int col = n0 + wc * 64 + n * 16 + l15;
        #pragma unroll
        for (int mi = 0; mi < 4; ++mi) {
            const int mb = m0 + wr * 64 + mi * 16 + l4 * 4;   // 4-aligned
            if (z == 1) {                                     // V^T
                const int bb = mb >> 12;
                const float bvc = bv[col];
                bf16x4 o;
                #pragma unroll
                for (int r = 0; r < 4; ++r) o[r] = (bf16)(acc[mi][n][r] + bvc);
                *(bf16x4*)(OutVt + ((size_t)bb * DM + col) * 4096 + (mb & 4095)) = o;
            } else if (z == 0) {                              // K
                const int bb = mb >> 12;
                const float s = bk[col] + dkv[bb * DM + col];
                #pragma unroll
                for (int r = 0; r < 4; ++r)
                    OutK[(size_t)(mb + r) * DM + col] = (bf16)(acc[mi][n][r] + s);
            } else {                                          // Q (batch=1024 rows)
                const int bb = mb >> 10;
                const float s = bq[col] + dq[bb * DM + col];
                #pragma unroll
                for (int r = 0; r < 4; ++r)
                    OutQ[(size_t)(mb + r) * DM + col] = (bf16)((acc[mi][n][r] + s) * QSCALE);
            }
        }
    }
}

// ---------------------------------------------------------------------------
// Flash attention v4d: round-17 structure (proven 78us) + T5 s_setprio around
// the two MFMA clusters (m191: attn-positive; blocks independent -> role
// diversity). Everything else unchanged.
// ---------------------------------------------------------------------------
__global__ __launch_bounds__(256) void attn_kernel(
    const bf16* __restrict__ Qb, const bf16* __restrict__ Kb,
    const bf16* __restrict__ Vt, const u64* __restrict__ mbits,
    const u64* __restrict__ cbits, bf16* __restrict__ PO, float* __restrict__ PL)
{
    __shared__ __align__(16) char sm[32768];   // 2 x (8KB K | 8KB V)

    const int tid  = threadIdx.x;
    const int lane = tid & 63;
    const int wave = tid >> 6;
    const int l31  = lane & 31;
    const int hi   = lane >> 5;

    // 1024 blocks = 8 XCD x 4 pairs x (8 g-tiles x 4 S-quarters).
    const int flat = blockIdx.x;
    const int xcd  = flat & 7;
    const int slot = flat >> 3;               // 0..127
    const int pr   = xcd * 4 + (slot >> 5);   // (b,h) pair 0..31
    const int sub  = slot & 31;               // gt*4 + squarter
    const int b    = pr >> 3;
    const int h    = pr & 7;
    const int g0   = (sub >> 2) * 128;
    const int tb   = (sub & 3) * 16;          // tile base (S-quarter, 16 tiles)
    const int blkid = pr * 32 + sub;          // scratch slot 0..1023

    // Q B-frags: q = g0 + wave*32 + l31 (Q pre-scaled 0.125*log2e)
    const bf16* qbase = Qb + (size_t)(b * G_LEN + g0 + wave * 32 + l31) * DM + h * DK + 8 * hi;
    const bf16x8 qf0 = *(const bf16x8*)(qbase);
    const bf16x8 qf1 = *(const bf16x8*)(qbase + 16);
    const bf16x8 qf2 = *(const bf16x8*)(qbase + 32);
    const bf16x8 qf3 = *(const bf16x8*)(qbase + 48);

    const bf16* Kh = Kb + (size_t)b * S_LEN * DM + h * DK;
    const bf16* Vh = Vt + (size_t)(b * NH + h) * DK * S_LEN;
    const u64*  mbv = mbits + b * (S_LEN / 64);
    const u64*  cbv = cbits + (size_t)(g0 + wave * 32 + l31) * (S_LEN / 64);

    // Staging: waves 0,1 stage K rows, waves 2,3 stage V rows.
    const bool isK    = (wave < 2);
    const int rowbase = (wave & 1) * 32 + (lane >> 3);
    const int col16s  = (lane & 7) ^ (rowbase & 7);
    const int swz     = l31 & 7;   // read-side swizzle key

#define STAGE(tt, bufi) do {                                                   \
    char* ldw = sm + (bufi) * 16384 + wave * 4096;                             \
    _Pragma("unroll")                                                          \
    for (int i = 0; i < 4; ++i) {                                              \
        const int row = rowbase + i * 8;                                       \
        const bf16* g = isK                                                    \
            ? (Kh + (size_t)((tt) * 64 + row) * DM + col16s * 8)               \
            : (Vh + (size_t)row * S_LEN + (tt) * 64 + col16s * 8);             \
        stage16(g, ldw + i * 1024);                                            \
    }                                                                          \
} while (0)

    f32x16 accA = {};   // d = l31
    f32x16 accB = {};   // d = 32 + l31
    float lsum = 0.f;

    // prologue: tile tb in flight
    STAGE(tb + 0, 0);

    for (int t = 0; t < 16; ++t) {
        __builtin_amdgcn_s_barrier();              // all waves done reading buf[(t+1)&1]
        __builtin_amdgcn_sched_barrier(0);
        if (t + 1 < 16) {
            STAGE(tb + t + 1, (t + 1) & 1);
            asm volatile("s_waitcnt vmcnt(4)" ::: "memory");   // tile t staged; t+1 in flight
        } else {
            asm volatile("s_waitcnt vmcnt(0)" ::: "memory");
        }
        __builtin_amdgcn_s_barrier();              // buf[t&1] staged for all waves
        __builtin_amdgcn_sched_barrier(0);

        const char* bK = sm + (t & 1) * 16384;
        const char* bV = bK + 8192;

        // ---- QK^T (A = K from LDS, swizzled read): D[s_sub][q]
#define KF(ss, m) (*(const bf16x8*)(bK + ((ss) * 32 + l31) * 128 + (((2 * (m) + hi) ^ swz) * 16)))
        f32x16 c0 = {}, c1 = {};
        __builtin_amdgcn_s_setprio(1);
        c0 = mfma32(KF(0, 0), qf0, c0); c0 = mfma32(KF(0, 1), qf1, c0);
        c0 = mfma32(KF(0, 2), qf2, c0); c0 = mfma32(KF(0, 3), qf3, c0);
        c1 = mfma32(KF(1, 0), qf0, c1); c1 = mfma32(KF(1, 1), qf1, c1);
        c1 = mfma32(KF(1, 2), qf2, c1); c1 = mfma32(KF(1, 3), qf3, c1);
        __builtin_amdgcn_s_setprio(0);

        // ---- masks: one u64 per 64-s tile
        const u64 w64 = cbv[tb + t] & mbv[tb + t];
        const uint32_t kw0 = ((uint32_t)w64) >> (4 * hi);
        const uint32_t kw1 = ((uint32_t)(w64 >> 32)) >> (4 * hi);

        bf16x8 pa0, pa1, pb0, pb1;
        exppack(c0, kw0, lsum, pa0, pa1);
        exppack(c1, kw1, lsum, pb0, pb1);

        // ---- PV (B = V from LDS, swizzled read): acc[q][d]
#define VF(ss, ks, dh) (*(const bf16x8*)(bV + ((dh) * 32 + l31) * 128 + ((((ss) * 4 + (ks) * 2 + hi) ^ swz) * 16)))
        __builtin_amdgcn_s_setprio(1);
        accA = mfma32(pa0, VF(0, 0, 0), accA); accA = mfma32(pa1, VF(0, 1, 0), accA);
        accA = mfma32(pb0, VF(1, 0, 0), accA); accA = mfma32(pb1, VF(1, 1, 0), accA);
        accB = mfma32(pa0, VF(0, 0, 1), accB); accB = mfma32(pa1, VF(0, 1, 1), accB);
        accB = mfma32(pb0, VF(1, 0, 1), accB); accB = mfma32(pb1, VF(1, 1, 1), accB);
        __builtin_amdgcn_s_setprio(0);
    }
#undef KF
#undef VF
#undef STAGE

    // ---- write partials ----
    const float tl = lsum + __shfl_xor(lsum, 32);
    if (hi == 0) PL[blkid * 128 + wave * 32 + l31] = tl;
    bf16* po = PO + (size_t)blkid * 8192 + (wave * 32) * 64;
    #pragma unroll
    for (int reg = 0; reg < 16; ++reg) {
        const int q = (reg & 3) + 8 * (reg >> 2) + 4 * hi;
        po[q * 64 + l31]      = (bf16)accA[reg];
        po[q * 64 + 32 + l31] = (bf16)accB[reg];
    }
}

// ---------------------------------------------------------------------------
// Merge the four S-quarter partials -> AO. 2M elements, 4 per thread.
// ---------------------------------------------------------------------------
__global__ __launch_bounds__(256) void attn_merge(
    const bf16* __restrict__ PO, const float* __restrict__ PL, bf16* __restrict__ AO)
{
    const int idx = (blockIdx.x * 256 + threadIdx.x) * 4;   // 4 consecutive d
    const int row = idx >> 9;          // 0..4095 = b*1024 + g
    const int col = idx & 511;         // h*64 + d
    const int h   = col >> 6;
    const int d   = col & 63;
    const int pr  = (row >> 10) * 8 + h;
    const int gt  = (row & 1023) >> 7;
    const int q   = row & 127;
    const int slot0 = pr * 32 + gt * 4;
    float num[4] = {0.f, 0.f, 0.f, 0.f};
    float pl = 0.f;
    #pragma unroll
    for (int s = 0; s < 4; ++s) {
        const bf16x4 n = *(const bf16x4*)(PO + (size_t)(slot0 + s) * 8192 + q * 64 + d);
        #pragma unroll
        for (int j = 0; j < 4; ++j) num[j] += (float)n[j];
        pl += PL[(slot0 + s) * 128 + q];
    }
    const float inv = pl > 0.f ? 1.f / pl : 0.f;
    bf16x4 o;
    #pragma unroll
    for (int j = 0; j < 4; ++j) o[j] = (bf16)(num[j] * inv);
    *(bf16x4*)(AO + (size_t)row * 512 + col) = o;
}

// ---------------------------------------------------------------------------
// Row LayerNorm: one block per row (512 cols), 256 threads.
// ---------------------------------------------------------------------------
__global__ __launch_bounds__(256) void out_ln(
    const float* __restrict__ Y, const float* __restrict__ gam,
    const float* __restrict__ bet, float* __restrict__ out)
{
    const int row = blockIdx.x;
    const int tid = threadIdx.x;
    const float x0 = Y[(size_t)row * DM + tid];
    const float x1 = Y[(size_t)row * DM + 256 + tid];
    float s  = x0 + x1;
    float sq = x0 * x0 + x1 * x1;
    #pragma unroll
    for (int off = 1; off < 64; off <<= 1) {
        s  += __shfl_xor(s, off);
        sq += __shfl_xor(sq, off);
    }
    __shared__ float ss[4], ssq[4];
    const int wave = tid >> 6;
    if ((tid & 63) == 0) { ss[wave] = s; ssq[wave] = sq; }
    __syncthreads();
    s  = ss[0] + ss[1] + ss[2] + ss[3];
    sq = ssq[0] + ssq[1] + ssq[2] + ssq[3];
    const float mu  = s * (1.f / 512.f);
    const float var = sq * (1.f / 512.f) - mu * mu;
    const float rs  = rsqrtf(var + 1e-5f);
    out[(size_t)row * DM + tid]       = (x0 - mu) * rs * gam[tid] + bet[tid];
    out[(size_t)row * DM + 256 + tid] = (x1 - mu) * rs * gam[tid + 256] + bet[tid + 256];
}

// ---------------------------------------------------------------------------
extern "C" void kernel_launch(void* const* d_in, const int* in_sizes, int n_in,
                              void* d_out, int out_size, void* d_ws, size_t ws_size,
                              hipStream_t stream) {
    const float* queries     = (const float*)d_in[0];   // [4,1024,512]
    const float* keys_values = (const float*)d_in[1];   // [4,4096,512]
    const float* dq          = (const float*)d_in[2];   // [4,1,512]
    const float* dk          = (const float*)d_in[3];   // [4,1,512]
    const int*   mask        = (const int*)d_in[4];     // [4,4096]
    const void*  cis         = d_in[5];                 // [1024,4096] bool (dtype detected)
    const float* wq_w = (const float*)d_in[6];
    const float* wq_b = (const float*)d_in[7];
    const float* wk_w = (const float*)d_in[8];
    const float* wk_b = (const float*)d_in[9];
    const float* wv_w = (const float*)d_in[10];
    const float* wv_b = (const float*)d_in[11];
    const float* wo_w = (const float*)d_in[12];
    const float* wo_b = (const float*)d_in[13];
    const float* ln_g = (const float*)d_in[14];
    const float* ln_b = (const float*)d_in[15];
    float* out = (float*)d_out;

    char* ws = (char*)d_ws;
    bf16*  Qbf = (bf16*)(ws);                                   //  4 MB (pre-scaled x0.125*log2e)
    bf16*  Kbf = (bf16*)(ws + (4u << 20));                      // 16 MB [16384,512]
    bf16*  Vt  = (bf16*)(ws + (20u << 20));                     // 16 MB [4,8,64,4096]
    bf16*  AO  = (bf16*)(ws + (36u << 20));                     //  4 MB [4096,512]
    bf16*  Xq  = (bf16*)(ws + (36u << 20));                     //  4 MB (overlays AO; dead
                                                                //        before merge writes AO)
    bf16*  PO  = (bf16*)(ws + (40u << 20));                     // 16 MB partial numerators
    bf16*  Xkv = (bf16*)(ws + (40u << 20));                     // 16 MB (overlays PO; dead
                                                                //        before attn writes PO)
    float* Yw  = (float*)(ws + (40u << 20));                    //  8 MB (overlays PO; PO dead
                                                                //        before O-proj writes Yw)
    u64*   mbits   = (u64*)(ws + (56u << 20) + 4096);           //  2 KB [4][64]
    u64*   cbits   = (u64*)(ws + (56u << 20) + 8192);           // 512 KB [1024][64]
    float* PL      = (float*)(ws + (56u << 20) + 544 * 1024);   // 512 KB [1024][128]
    bf16*  Wb4     = (bf16*)(ws + (58u << 20));                 //  2 MB: wq|wk|wv|wo bf16
    bf16*  Wqb = Wb4;
    bf16*  Wkb = Wb4 + (size_t)NW_EL;
    bf16*  Wvb = Wb4 + (size_t)2 * NW_EL;
    bf16*  Wob = Wb4 + (size_t)3 * NW_EL;

    // One prep dispatch: mask packing (inline dtype detect) + f32->bf16 casts.
    prep<<<PACK_BLOCKS + CVT_BLOCKS, 256, 0, stream>>>(
        cis, mask, queries, keys_values, wq_w, wk_w, wv_w, wo_w,
        cbits, mbits, Xq, Xkv, Wb4);

    // Combined K+V+Q projections: one dispatch, gridDim.z=3.
    gemm_kvq128<<<dim3(128, 4, 3), 256, 0, stream>>>(
        Xkv, Xq, Wkb, wk_b, dk, Wvb, wv_b, Wqb, wq_b, dq, Kbf, Vt, Qbf);

    // Fused masked flash attention (4-way S-split, round-14 rhythm, raw v_exp,
    // setprio around MFMA clusters)
    attn_kernel<<<1024, 256, 0, stream>>>(Qbf, Kbf, Vt, mbits, cbits, PO, PL);
    attn_merge<<<2048, 256, 0, stream>>>(PO, PL, AO);

    // Output projection (all-bf16 64-tile) -> f32 scratch (overwrites PO, now dead)
    gemm64<1, 1024><<<dim3(64, 8), 256, 0, stream>>>(AO, Wob, wo_b, nullptr, Yw, 1.0f);

    // LayerNorm -> d_out
    out_ln<<<4096, 256, 0, stream>>>(Yw, ln_g, ln_b, out);
}

// Round 20
// 136.664 us; speedup vs baseline: 1.6574x; 1.0153x over previous
//
#include <hip/hip_runtime.h>
#include <stdint.h>
#include <stddef.h>

typedef __bf16 bf16;
typedef __bf16 bf16x4 __attribute__((ext_vector_type(4)));
typedef __bf16 bf16x8 __attribute__((ext_vector_type(8)));
typedef float f32x4 __attribute__((ext_vector_type(4)));
typedef float f32x16 __attribute__((ext_vector_type(16)));
typedef unsigned long long u64;

#define BATCH 4
#define G_LEN 1024
#define S_LEN 4096
#define DM 512
#define NH 8
#define DK 64
#define CIS_WORDS (G_LEN * (S_LEN / 64))   // 65536
#define NQ_EL  (BATCH * G_LEN * DM)        // 2,097,152
#define NKV_EL (BATCH * S_LEN * DM)        // 8,388,608
#define NW_EL  (DM * DM)                   // 262,144
#define PACK_BLOCKS ((CIS_WORDS + BATCH * (S_LEN / 64) + 3) / 4)   // 16448
#define CVT_BLOCKS  ((NQ_EL + NKV_EL + 4 * NW_EL) / 2048)          // 5632
#define QSCALE (0.125f * 1.44269504f)

__device__ __forceinline__ f32x4 mfma16(bf16x8 a, bf16x8 b, f32x4 c) {
    return __builtin_amdgcn_mfma_f32_16x16x32_bf16(a, b, c, 0, 0, 0);
}
__device__ __forceinline__ f32x16 mfma32(bf16x8 a, bf16x8 b, f32x16 c) {
    return __builtin_amdgcn_mfma_f32_32x32x16_bf16(a, b, c, 0, 0, 0);
}
// v_cvt_pk_bf16_f32: dst.lo = bf16(lo), dst.hi = bf16(hi). No builtin (m240).
__device__ __forceinline__ uint32_t cvtpk(float lo, float hi_) {
    uint32_t r;
    asm("v_cvt_pk_bf16_f32 %0, %1, %2" : "=v"(r) : "v"(lo), "v"(hi_));
    return r;
}
// v_permlane32_swap_b32: a.lanes[32:64] <-> b.lanes[0:32] (gfx950).
__device__ __forceinline__ void pswap(uint32_t& a, uint32_t& b) {
    asm("v_permlane32_swap_b32 %0, %1" : "+v"(a), "+v"(b));
}
// raw v_exp_f32 (= exp2): round-17 proven (78us vs OCML exp2f's 99us).
__device__ __forceinline__ float fexp2(float x) {
    float r;
    asm("v_exp_f32 %0, %1" : "=v"(r) : "v"(x));
    return r;
}
__device__ __forceinline__ bf16x8 mk8(uint32_t a, uint32_t b, uint32_t c, uint32_t d) {
    union { uint32_t u[4]; bf16x8 v; } x;
    x.u[0] = a; x.u[1] = b; x.u[2] = c; x.u[3] = d;
    return x.v;
}
// masked exp2 + bf16 pack + permlane redistribute into PV A-fragments.
__device__ __forceinline__ void exppack(f32x16& c, uint32_t kw, float& lsum,
                                        bf16x8& pa0, bf16x8& pa1) {
    #pragma unroll
    for (int reg = 0; reg < 16; ++reg) {
        const int bit = (reg & 3) + 8 * (reg >> 2);
        const float e = fexp2(c[reg]);
        c[reg] = ((kw >> bit) & 1u) ? e : 0.f;
    }
    lsum += ((c[0] + c[1]) + (c[2] + c[3])) + ((c[4] + c[5]) + (c[6] + c[7]))
          + ((c[8] + c[9]) + (c[10] + c[11])) + ((c[12] + c[13]) + (c[14] + c[15]));
    uint32_t wa0 = cvtpk(c[0],  c[1]),  wa1 = cvtpk(c[2],  c[3]);
    uint32_t wb0 = cvtpk(c[4],  c[5]),  wb1 = cvtpk(c[6],  c[7]);
    uint32_t wc0 = cvtpk(c[8],  c[9]),  wc1 = cvtpk(c[10], c[11]);
    uint32_t wd0 = cvtpk(c[12], c[13]), wd1 = cvtpk(c[14], c[15]);
    pswap(wa0, wb0); pswap(wa1, wb1); pswap(wc0, wd0); pswap(wc1, wd1);
    pa0 = mk8(wa0, wa1, wb0, wb1);   // s = 8hi + 0..7
    pa1 = mk8(wc0, wc1, wd0, wd1);   // s = 16 + 8hi + 0..7
}
// async global->LDS, 16B/lane. LDS dest is WAVE-UNIFORM base (HW adds lane*16).
__device__ __forceinline__ void stage16(const bf16* g, char* l) {
    __builtin_amdgcn_global_load_lds(
        (const __attribute__((address_space(1))) void*)g,
        (__attribute__((address_space(3))) void*)l, 16, 0, 0);
}

// ---------------------------------------------------------------------------
// ONE prep dispatch (round-19, proven): pack cis+mask bits (inline dtype
// detect) + f32->bf16 casts of all GEMM operands.
// ---------------------------------------------------------------------------
__global__ __launch_bounds__(256) void prep(
    const void* __restrict__ cisv, const int* __restrict__ mask,
    const float* __restrict__ q, const float* __restrict__ kv,
    const float* __restrict__ wq, const float* __restrict__ wk,
    const float* __restrict__ wv, const float* __restrict__ wo,
    u64* __restrict__ cbits, u64* __restrict__ mbits,
    bf16* __restrict__ oq, bf16* __restrict__ okv, bf16* __restrict__ ow4)
{
    const int bid = blockIdx.x;
    if (bid < PACK_BLOCKS) {
        const unsigned char* cis8 = (const unsigned char*)cisv;
        const int lane = threadIdx.x & 63;
        const int is_byte = __any((int)cis8[4 * lane + 1]);   // wave-uniform
        const int wid = bid * 4 + (threadIdx.x >> 6);
        if (wid < CIS_WORDS) {
            int v;
            if (is_byte) v = cis8[(size_t)wid * 64 + lane];
            else         v = ((const int*)cisv)[(size_t)wid * 64 + lane];
            const u64 bits = __ballot(v != 0);
            if (lane == 0) cbits[wid] = bits;
        } else if (wid < CIS_WORDS + BATCH * (S_LEN / 64)) {
            const int w2 = wid - CIS_WORDS;               // b*64 + sw
            const u64 bits = __ballot(mask[w2 * 64 + lane] != 0);
            if (lane == 0) mbits[w2] = bits;
        }
        return;
    }
    const size_t e = ((size_t)(bid - PACK_BLOCKS) * 256 + threadIdx.x) * 8;
    const float* src;
    bf16* dst;
    size_t off;
    if (e < NQ_EL)               { src = q;  dst = oq;  off = e; }
    else if (e < NQ_EL + NKV_EL) { src = kv; dst = okv; off = e - NQ_EL; }
    else {
        const size_t w = e - NQ_EL - NKV_EL;
        const int wi = (int)(w / NW_EL);
        off = w % NW_EL;
        src = (wi == 0) ? wq : (wi == 1) ? wk : (wi == 2) ? wv : wo;
        dst = ow4 + (size_t)wi * NW_EL;
    }
    const float4 a = *(const float4*)(src + off);
    const float4 b = *(const float4*)(src + off + 4);
    bf16x8 o;
    o[0] = (bf16)a.x; o[1] = (bf16)a.y; o[2] = (bf16)a.z; o[3] = (bf16)a.w;
    o[4] = (bf16)b.x; o[5] = (bf16)b.y; o[6] = (bf16)b.z; o[7] = (bf16)b.w;
    *(bf16x8*)(dst + off) = o;
}

// ---------------------------------------------------------------------------
// All-bf16 64x64-tile GEMM (O-proj): 512 blocks = 2/CU; pure bf16x8 staging.
// ---------------------------------------------------------------------------
template<int OUT_F32, int ROWS_PER_B>
__global__ __launch_bounds__(256) void gemm64(
    const bf16* __restrict__ A, const bf16* __restrict__ B,
    const float* __restrict__ bias, const float* __restrict__ shift,
    void* __restrict__ Out, float oscale)
{
    __shared__ bf16 As[64][72];
    __shared__ bf16 Bs[64][72];
    const int tid  = threadIdx.x;
    const int lane = tid & 63;
    const int wave = tid >> 6;
    const int l15  = lane & 15;
    const int l4   = lane >> 4;
    const int m0   = blockIdx.x * 64;
    const int n0   = blockIdx.y * 64;

    f32x4 acc[4] = {};

    for (int kt = 0; kt < DM; kt += 64) {
        #pragma unroll
        for (int i = 0; i < 2; ++i) {
            const int q   = tid + i * 256;
            const int row = q >> 3;
            const int kq  = (q & 7) * 8;
            *(bf16x8*)&As[row][kq] = *(const bf16x8*)(A + (size_t)(m0 + row) * DM + kt + kq);
            *(bf16x8*)&Bs[row][kq] = *(const bf16x8*)(B + (size_t)(n0 + row) * DM + kt + kq);
        }
        __syncthreads();
        #pragma unroll
        for (int ks = 0; ks < 64; ks += 32) {
            const bf16x8 a = *(const bf16x8*)&As[wave * 16 + l15][ks + 8 * l4];
            #pragma unroll
            for (int n = 0; n < 4; ++n) {
                const bf16x8 b = *(const bf16x8*)&Bs[n * 16 + l15][ks + 8 * l4];
                acc[n] = mfma16(a, b, acc[n]);
            }
        }
        __syncthreads();
    }

    #pragma unroll
    for (int n = 0; n < 4; ++n) {
        const int col = n0 + n * 16 + l15;
        const float bv = bias[col];
        #pragma unroll
        for (int r = 0; r < 4; ++r) {
            const int m = m0 + wave * 16 + l4 * 4 + r;
            float v = acc[n][r] + bv;
            if (shift) v += shift[(m / ROWS_PER_B) * DM + col];
            v *= oscale;
            if (OUT_F32) ((float*)Out)[(size_t)m * DM + col] = v;
            else         ((bf16*)Out)[(size_t)m * DM + col] = (bf16)v;
        }
    }
}

// ---------------------------------------------------------------------------
// K+V+Q projections, round-20: global_load_lds staging (m97 lever: +67% on
// this exact 128^2 structure) with the attn kernel's PROVEN swizzle/barrier
// machinery. LDS = 2 x (16KB A | 16KB B) unpadded [128 rows][8 slots x 16B];
// source pre-swizzle slot^(row&7), read-side same involution -> 2-way-free
// ds_read_b128. Two-barrier rhythm, vmcnt(8) AFTER next-tile STAGE issue.
// gridDim.z = 3: z=0 K (+dk), z=1 V^T, z=2 Q (x<32; +dq, *QSCALE).
// ---------------------------------------------------------------------------
__global__ __launch_bounds__(256) void gemm_kvq128(
    const bf16* __restrict__ Xkv, const bf16* __restrict__ Xq,
    const bf16* __restrict__ Wk, const float* __restrict__ bk, const float* __restrict__ dkv,
    const bf16* __restrict__ Wv, const float* __restrict__ bv,
    const bf16* __restrict__ Wq, const float* __restrict__ bq, const float* __restrict__ dq,
    bf16* __restrict__ OutK, bf16* __restrict__ OutVt, bf16* __restrict__ OutQ)
{
    const int z = blockIdx.z;
    if (z == 2 && blockIdx.x >= 32) return;   // Q: M=4096 -> 32 x-tiles

    __shared__ __align__(16) char sm[65536];   // 2 x (16KB A | 16KB B)

    const int tid  = threadIdx.x;
    const int lane = tid & 63;
    const int wave = tid >> 6;
    const int l15  = lane & 15;
    const int l4   = lane >> 4;
    const int wr   = wave >> 1;
    const int wc   = wave & 1;
    const int m0   = blockIdx.x * 128;
    const int n0   = blockIdx.y * 128;
    const bf16* X = (z == 2) ? Xq : Xkv;
    const bf16* W = (z == 0) ? Wk : (z == 1) ? Wv : Wq;

    // Staging: waves 0,1 stage A rows [0,64)/[64,128); waves 2,3 stage B.
    // lds: half + (wave&1)*8192 + i*1024 + lane*16 -> row=(wave&1)*64+i*8+(lane>>3),
    // slot=lane&7. Source pre-swizzle: chunk = (lane&7)^(row&7), row&7=(lane>>3).
    const bf16* gs  = ((wave < 2) ? X : W)
                    + (size_t)(((wave < 2) ? m0 : n0) + (wave & 1) * 64 + (lane >> 3)) * DM
                    + ((lane & 7) ^ (lane >> 3)) * 8;
    const int lhalf = (wave < 2 ? 0 : 16384) + (wave & 1) * 8192;

#define STAGE(kt_, bufi) do {                                                  \
    char* ldw = sm + (bufi) * 32768 + lhalf;                                   \
    _Pragma("unroll")                                                          \
    for (int i = 0; i < 8; ++i)                                                \
        stage16(gs + (kt_) * 64 + (size_t)i * 8 * DM, ldw + i * 1024);         \
} while (0)

    f32x4 acc[4][4] = {};

    STAGE(0, 0);
    for (int kt = 0; kt < 8; ++kt) {
        __builtin_amdgcn_s_barrier();              // all waves done reading other buf
        __builtin_amdgcn_sched_barrier(0);
        if (kt + 1 < 8) {
            STAGE(kt + 1, (kt + 1) & 1);
            asm volatile("s_waitcnt vmcnt(8)" ::: "memory");   // tile kt staged
        } else {
            asm volatile("s_waitcnt vmcnt(0)" ::: "memory");
        }
        __builtin_amdgcn_s_barrier();              // buf[kt&1] visible to all
        __builtin_amdgcn_sched_barrier(0);

        const char* bA = sm + (kt & 1) * 32768;
        const char* bB = bA + 16384;
        #pragma unroll
        for (int ks = 0; ks < 64; ks += 32) {
            const int slotx = (4 * (ks >> 5) + l4) ^ (l15 & 7);  // read swizzle
            bf16x8 af[4];
            #pragma unroll
            for (int mi = 0; mi < 4; ++mi)
                af[mi] = *(const bf16x8*)(bA + (wr * 64 + mi * 16 + l15) * 128 + slotx * 16);
            #pragma unroll
            for (int n = 0; n < 4; ++n) {
                const bf16x8 b = *(const bf16x8*)(bB + (wc * 64 + n * 16 + l15) * 128 + slotx * 16);
                #pragma unroll
                for (int mi = 0; mi < 4; ++mi)
                    acc[mi][n] = mfma16(af[mi], b, acc[mi][n]);
            }
        }
    }
#undef STAGE

    #pragma unroll
    for (int n = 0; n < 4; ++n) {
        const int col = n0 + wc * 64 + n * 16 + l15;
        #pragma unroll
        for (int mi = 0; mi < 4; ++mi) {
            const int mb = m0 + wr * 64 + mi * 16 + l4 * 4;   // 4-aligned
            if (z == 1) {                                     // V^T
                const int bb = mb >> 12;
                const float bvc = bv[col];
                bf16x4 o;
                #pragma unroll
                for (int r = 0; r < 4; ++r) o[r] = (bf16)(acc[mi][n][r] + bvc);
                *(bf16x4*)(OutVt + ((size_t)bb * DM + col) * 4096 + (mb & 4095)) = o;
            } else if (z == 0) {                              // K
                const int bb = mb >> 12;
                const float s = bk[col] + dkv[bb * DM + col];
                #pragma unroll
                for (int r = 0; r < 4; ++r)
                    OutK[(size_t)(mb + r) * DM + col] = (bf16)(acc[mi][n][r] + s);
            } else {                                          // Q (batch=1024 rows)
                const int bb = mb >> 10;
                const float s = bq[col] + dq[bb * DM + col];
                #pragma unroll
                for (int r = 0; r < 4; ++r)
                    OutQ[(size_t)(mb + r) * DM + col] = (bf16)((acc[mi][n][r] + s) * QSCALE);
            }
        }
    }
}

// ---------------------------------------------------------------------------
// Flash attention v4d (round-19, proven 77.5us): 4-way S-split, 2x16KB dbuf,
// two-barrier rhythm w/ vmcnt(4) after STAGE, raw v_exp, setprio clusters.
// UNCHANGED.
// ---------------------------------------------------------------------------
__global__ __launch_bounds__(256) void attn_kernel(
    const bf16* __restrict__ Qb, const bf16* __restrict__ Kb,
    const bf16* __restrict__ Vt, const u64* __restrict__ mbits,
    const u64* __restrict__ cbits, bf16* __restrict__ PO, float* __restrict__ PL)
{
    __shared__ __align__(16) char sm[32768];   // 2 x (8KB K | 8KB V)

    const int tid  = threadIdx.x;
    const int lane = tid & 63;
    const int wave = tid >> 6;
    const int l31  = lane & 31;
    const int hi   = lane >> 5;

    // 1024 blocks = 8 XCD x 4 pairs x (8 g-tiles x 4 S-quarters).
    const int flat = blockIdx.x;
    const int xcd  = flat & 7;
    const int slot = flat >> 3;               // 0..127
    const int pr   = xcd * 4 + (slot >> 5);   // (b,h) pair 0..31
    const int sub  = slot & 31;               // gt*4 + squarter
    const int b    = pr >> 3;
    const int h    = pr & 7;
    const int g0   = (sub >> 2) * 128;
    const int tb   = (sub & 3) * 16;          // tile base (S-quarter, 16 tiles)
    const int blkid = pr * 32 + sub;          // scratch slot 0..1023

    // Q B-frags: q = g0 + wave*32 + l31 (Q pre-scaled 0.125*log2e)
    const bf16* qbase = Qb + (size_t)(b * G_LEN + g0 + wave * 32 + l31) * DM + h * DK + 8 * hi;
    const bf16x8 qf0 = *(const bf16x8*)(qbase);
    const bf16x8 qf1 = *(const bf16x8*)(qbase + 16);
    const bf16x8 qf2 = *(const bf16x8*)(qbase + 32);
    const bf16x8 qf3 = *(const bf16x8*)(qbase + 48);

    const bf16* Kh = Kb + (size_t)b * S_LEN * DM + h * DK;
    const bf16* Vh = Vt + (size_t)(b * NH + h) * DK * S_LEN;
    const u64*  mbv = mbits + b * (S_LEN / 64);
    const u64*  cbv = cbits + (size_t)(g0 + wave * 32 + l31) * (S_LEN / 64);

    // Staging: waves 0,1 stage K rows, waves 2,3 stage V rows.
    const bool isK    = (wave < 2);
    const int rowbase = (wave & 1) * 32 + (lane >> 3);
    const int col16s  = (lane & 7) ^ (rowbase & 7);
    const int swz     = l31 & 7;   // read-side swizzle key

#define STAGE(tt, bufi) do {                                                   \
    char* ldw = sm + (bufi) * 16384 + wave * 4096;                             \
    _Pragma("unroll")                                                          \
    for (int i = 0; i < 4; ++i) {                                              \
        const int row = rowbase + i * 8;                                       \
        const bf16* g = isK                                                    \
            ? (Kh + (size_t)((tt) * 64 + row) * DM + col16s * 8)               \
            : (Vh + (size_t)row * S_LEN + (tt) * 64 + col16s * 8);             \
        stage16(g, ldw + i * 1024);                                            \
    }                                                                          \
} while (0)

    f32x16 accA = {};   // d = l31
    f32x16 accB = {};   // d = 32 + l31
    float lsum = 0.f;

    // prologue: tile tb in flight
    STAGE(tb + 0, 0);

    for (int t = 0; t < 16; ++t) {
        __builtin_amdgcn_s_barrier();              // all waves done reading buf[(t+1)&1]
        __builtin_amdgcn_sched_barrier(0);
        if (t + 1 < 16) {
            STAGE(tb + t + 1, (t + 1) & 1);
            asm volatile("s_waitcnt vmcnt(4)" ::: "memory");   // tile t staged; t+1 in flight
        } else {
            asm volatile("s_waitcnt vmcnt(0)" ::: "memory");
        }
        __builtin_amdgcn_s_barrier();              // buf[t&1] staged for all waves
        __builtin_amdgcn_sched_barrier(0);

        const char* bK = sm + (t & 1) * 16384;
        const char* bV = bK + 8192;

        // ---- QK^T (A = K from LDS, swizzled read): D[s_sub][q]
#define KF(ss, m) (*(const bf16x8*)(bK + ((ss) * 32 + l31) * 128 + (((2 * (m) + hi) ^ swz) * 16)))
        f32x16 c0 = {}, c1 = {};
        __builtin_amdgcn_s_setprio(1);
        c0 = mfma32(KF(0, 0), qf0, c0); c0 = mfma32(KF(0, 1), qf1, c0);
        c0 = mfma32(KF(0, 2), qf2, c0); c0 = mfma32(KF(0, 3), qf3, c0);
        c1 = mfma32(KF(1, 0), qf0, c1); c1 = mfma32(KF(1, 1), qf1, c1);
        c1 = mfma32(KF(1, 2), qf2, c1); c1 = mfma32(KF(1, 3), qf3, c1);
        __builtin_amdgcn_s_setprio(0);

        // ---- masks: one u64 per 64-s tile
        const u64 w64 = cbv[tb + t] & mbv[tb + t];
        const uint32_t kw0 = ((uint32_t)w64) >> (4 * hi);
        const uint32_t kw1 = ((uint32_t)(w64 >> 32)) >> (4 * hi);

        bf16x8 pa0, pa1, pb0, pb1;
        exppack(c0, kw0, lsum, pa0, pa1);
        exppack(c1, kw1, lsum, pb0, pb1);

        // ---- PV (B = V from LDS, swizzled read): acc[q][d]
#define VF(ss, ks, dh) (*(const bf16x8*)(bV + ((dh) * 32 + l31) * 128 + ((((ss) * 4 + (ks) * 2 + hi) ^ swz) * 16)))
        __builtin_amdgcn_s_setprio(1);
        accA = mfma32(pa0, VF(0, 0, 0), accA); accA = mfma32(pa1, VF(0, 1, 0), accA);
        accA = mfma32(pb0, VF(1, 0, 0), accA); accA = mfma32(pb1, VF(1, 1, 0), accA);
        accB = mfma32(pa0, VF(0, 0, 1), accB); accB = mfma32(pa1, VF(0, 1, 1), accB);
        accB = mfma32(pb0, VF(1, 0, 1), accB); accB = mfma32(pb1, VF(1, 1, 1), accB);
        __builtin_amdgcn_s_setprio(0);
    }
#undef KF
#undef VF
#undef STAGE

    // ---- write partials ----
    const float tl = lsum + __shfl_xor(lsum, 32);
    if (hi == 0) PL[blkid * 128 + wave * 32 + l31] = tl;
    bf16* po = PO + (size_t)blkid * 8192 + (wave * 32) * 64;
    #pragma unroll
    for (int reg = 0; reg < 16; ++reg) {
        const int q = (reg & 3) + 8 * (reg >> 2) + 4 * hi;
        po[q * 64 + l31]      = (bf16)accA[reg];
        po[q * 64 + 32 + l31] = (bf16)accB[reg];
    }
}

// ---------------------------------------------------------------------------
// Merge the four S-quarter partials -> AO. 2M elements, 4 per thread.
// ---------------------------------------------------------------------------
__global__ __launch_bounds__(256) void attn_merge(
    const bf16* __restrict__ PO, const float* __restrict__ PL, bf16* __restrict__ AO)
{
    const int idx = (blockIdx.x * 256 + threadIdx.x) * 4;   // 4 consecutive d
    const int row = idx >> 9;          // 0..4095 = b*1024 + g
    const int col = idx & 511;         // h*64 + d
    const int h   = col >> 6;
    const int d   = col & 63;
    const int pr  = (row >> 10) * 8 + h;
    const int gt  = (row & 1023) >> 7;
    const int q   = row & 127;
    const int slot0 = pr * 32 + gt * 4;
    float num[4] = {0.f, 0.f, 0.f, 0.f};
    float pl = 0.f;
    #pragma unroll
    for (int s = 0; s < 4; ++s) {
        const bf16x4 n = *(const bf16x4*)(PO + (size_t)(slot0 + s) * 8192 + q * 64 + d);
        #pragma unroll
        for (int j = 0; j < 4; ++j) num[j] += (float)n[j];
        pl += PL[(slot0 + s) * 128 + q];
    }
    const float inv = pl > 0.f ? 1.f / pl : 0.f;
    bf16x4 o;
    #pragma unroll
    for (int j = 0; j < 4; ++j) o[j] = (bf16)(num[j] * inv);
    *(bf16x4*)(AO + (size_t)row * 512 + col) = o;
}

// ---------------------------------------------------------------------------
// Row LayerNorm: one block per row (512 cols), 256 threads.
// ---------------------------------------------------------------------------
__global__ __launch_bounds__(256) void out_ln(
    const float* __restrict__ Y, const float* __restrict__ gam,
    const float* __restrict__ bet, float* __restrict__ out)
{
    const int row = blockIdx.x;
    const int tid = threadIdx.x;
    const float x0 = Y[(size_t)row * DM + tid];
    const float x1 = Y[(size_t)row * DM + 256 + tid];
    float s  = x0 + x1;
    float sq = x0 * x0 + x1 * x1;
    #pragma unroll
    for (int off = 1; off < 64; off <<= 1) {
        s  += __shfl_xor(s, off);
        sq += __shfl_xor(sq, off);
    }
    __shared__ float ss[4], ssq[4];
    const int wave = tid >> 6;
    if ((tid & 63) == 0) { ss[wave] = s; ssq[wave] = sq; }
    __syncthreads();
    s  = ss[0] + ss[1] + ss[2] + ss[3];
    sq = ssq[0] + ssq[1] + ssq[2] + ssq[3];
    const float mu  = s * (1.f / 512.f);
    const float var = sq * (1.f / 512.f) - mu * mu;
    const float rs  = rsqrtf(var + 1e-5f);
    out[(size_t)row * DM + tid]       = (x0 - mu) * rs * gam[tid] + bet[tid];
    out[(size_t)row * DM + 256 + tid] = (x1 - mu) * rs * gam[tid + 256] + bet[tid + 256];
}

// ---------------------------------------------------------------------------
extern "C" void kernel_launch(void* const* d_in, const int* in_sizes, int n_in,
                              void* d_out, int out_size, void* d_ws, size_t ws_size,
                              hipStream_t stream) {
    const float* queries     = (const float*)d_in[0];   // [4,1024,512]
    const float* keys_values = (const float*)d_in[1];   // [4,4096,512]
    const float* dq          = (const float*)d_in[2];   // [4,1,512]
    const float* dk          = (const float*)d_in[3];   // [4,1,512]
    const int*   mask        = (const int*)d_in[4];     // [4,4096]
    const void*  cis         = d_in[5];                 // [1024,4096] bool (dtype detected)
    const float* wq_w = (const float*)d_in[6];
    const float* wq_b = (const float*)d_in[7];
    const float* wk_w = (const float*)d_in[8];
    const float* wk_b = (const float*)d_in[9];
    const float* wv_w = (const float*)d_in[10];
    const float* wv_b = (const float*)d_in[11];
    const float* wo_w = (const float*)d_in[12];
    const float* wo_b = (const float*)d_in[13];
    const float* ln_g = (const float*)d_in[14];
    const float* ln_b = (const float*)d_in[15];
    float* out = (float*)d_out;

    char* ws = (char*)d_ws;
    bf16*  Qbf = (bf16*)(ws);                                   //  4 MB (pre-scaled x0.125*log2e)
    bf16*  Kbf = (bf16*)(ws + (4u << 20));                      // 16 MB [16384,512]
    bf16*  Vt  = (bf16*)(ws + (20u << 20));                     // 16 MB [4,8,64,4096]
    bf16*  AO  = (bf16*)(ws + (36u << 20));                     //  4 MB [4096,512]
    bf16*  Xq  = (bf16*)(ws + (36u << 20));                     //  4 MB (overlays AO; dead
                                                                //        before merge writes AO)
    bf16*  PO  = (bf16*)(ws + (40u << 20));                     // 16 MB partial numerators
    bf16*  Xkv = (bf16*)(ws + (40u << 20));                     // 16 MB (overlays PO; dead
                                                                //        before attn writes PO)
    float* Yw  = (float*)(ws + (40u << 20));                    //  8 MB (overlays PO; PO dead
                                                                //        before O-proj writes Yw)
    u64*   mbits   = (u64*)(ws + (56u << 20) + 4096);           //  2 KB [4][64]
    u64*   cbits   = (u64*)(ws + (56u << 20) + 8192);           // 512 KB [1024][64]
    float* PL      = (float*)(ws + (56u << 20) + 544 * 1024);   // 512 KB [1024][128]
    bf16*  Wb4     = (bf16*)(ws + (58u << 20));                 //  2 MB: wq|wk|wv|wo bf16
    bf16*  Wqb = Wb4;
    bf16*  Wkb = Wb4 + (size_t)NW_EL;
    bf16*  Wvb = Wb4 + (size_t)2 * NW_EL;
    bf16*  Wob = Wb4 + (size_t)3 * NW_EL;

    // One prep dispatch: mask packing (inline dtype detect) + f32->bf16 casts.
    prep<<<PACK_BLOCKS + CVT_BLOCKS, 256, 0, stream>>>(
        cis, mask, queries, keys_values, wq_w, wk_w, wv_w, wo_w,
        cbits, mbits, Xq, Xkv, Wb4);

    // Combined K+V+Q projections: one dispatch, gridDim.z=3, gload_lds staging.
    gemm_kvq128<<<dim3(128, 4, 3), 256, 0, stream>>>(
        Xkv, Xq, Wkb, wk_b, dk, Wvb, wv_b, Wqb, wq_b, dq, Kbf, Vt, Qbf);

    // Fused masked flash attention (4-way S-split, round-14 rhythm, raw v_exp,
    // setprio around MFMA clusters)
    attn_kernel<<<1024, 256, 0, stream>>>(Qbf, Kbf, Vt, mbits, cbits, PO, PL);
    attn_merge<<<2048, 256, 0, stream>>>(PO, PL, AO);

    // Output projection (all-bf16 64-tile) -> f32 scratch (overwrites PO, now dead)
    gemm64<1, 1024><<<dim3(64, 8), 256, 0, stream>>>(AO, Wob, wo_b, nullptr, Yw, 1.0f);

    // LayerNorm -> d_out
    out_ln<<<4096, 256, 0, stream>>>(Yw, ln_g, ln_b, out);
}